// Round 13
// baseline (396.291 us; speedup 1.0000x reference)
//
#include <hip/hip_runtime.h>

typedef unsigned short u16;
typedef unsigned int u32;
typedef short short8 __attribute__((ext_vector_type(8)));
typedef float f32x4 __attribute__((ext_vector_type(4)));

#define NB 64
#define NFB 257
#define NANG 360

template<int V> struct IC { static constexpr int value = V; };

__device__ __forceinline__ u16 f2bf(float x) {
    u32 u = __float_as_uint(x);
    u = (u + 0x7fffu + ((u >> 16) & 1u)) >> 16;
    return (u16)u;
}
__device__ __forceinline__ float bf2f(u16 h) { return __uint_as_float(((u32)h) << 16); }

// ---------------------------------------------------------------------------
// Unified activation layout: per pixel, (C/32) sections of 128 B:
//   [hi ch0-31 (64B) | lo ch0-31 (64B)] [hi ch32-63 | lo ch32-63] ...
// NUMERICS NOTE (round-10 failure): all convs must keep the full 3-term
// bf16 split (Ah*Bh + Ah*Bl + Al*Bh ~ f32 quality).  2-term (B rounded to
// bf16) produced 0.2%/layer error that flipped near-degenerate eigenvector
// subspaces in eigh -> 1/denom chaos -> doa absmax 171.  Do not retry.
// ---------------------------------------------------------------------------

// ---------------------------------------------------------------------------
// Fused prep: bnprep(4) | bpack1(6) | bpack c2(36) c3(36) c4(180) s2(243) |
// xpack(8320).  One launch, branch by block range.
// ---------------------------------------------------------------------------
__device__ __forceinline__ void bpack_body(
    const float* __restrict__ w, u16* __restrict__ Bp,
    int CREAL, int OCREAL, int NT, int KCC, int NFTOT, int i)
{
    int total = NT * KCC * 2 * NFTOT * 64;
    if (i >= total) return;
    int lane = i & 63;
    int t = i >> 6;
    int nf = t % NFTOT;
    int th = t / NFTOT;
    int h = th & 1;
    int chunk = th >> 1;
    int s = chunk / KCC, kc = chunk % KCC;
    int n = nf * 16 + (lane & 15);
    int k0 = kc * 32 + (lane >> 4) * 8;
    u16 o8[8];
    #pragma unroll
    for (int e = 0; e < 8; ++e) {
        int k = k0 + e;
        float v = 0.f;
        if (k < CREAL && n < OCREAL) v = w[((size_t)n * CREAL + k) * NT + s];
        u16 hh = f2bf(v);
        o8[e] = (h == 0) ? hh : f2bf(v - bf2f(hh));
    }
    u16* d = Bp + (size_t)i * 8;
    #pragma unroll
    for (int e = 0; e < 8; ++e) d[e] = o8[e];
}

__global__ __launch_bounds__(256) void prep_kernel(
    const float* __restrict__ X, u16* __restrict__ xp,
    const float* __restrict__ c1w, u16* __restrict__ bp1,
    const float* __restrict__ c2w, u16* __restrict__ bp2,
    const float* __restrict__ c3w, u16* __restrict__ bp3,
    const float* __restrict__ c4w, u16* __restrict__ bp4,
    const float* __restrict__ s2w, u16* __restrict__ bp5,
    const float* g1, const float* b1, const float* m1, const float* v1,
    const float* g2, const float* b2, const float* m2, const float* v2,
    const float* g3, const float* b3, const float* m3, const float* v3,
    const float* g4, const float* b4, const float* m4, const float* v4,
    float* __restrict__ bns)
{
    __shared__ float Xs[8][132];
    int blk = blockIdx.x;
    int tid = threadIdx.x;
    if (blk < 4) {
        int L = blk;
        const float* gs[4] = {g1, g2, g3, g4};
        const float* bs[4] = {b1, b2, b3, b4};
        const float* ms[4] = {m1, m2, m3, m4};
        const float* vs[4] = {v1, v2, v3, v4};
        int n = (L == 3) ? 257 : 64;
        float* sc = bns + L * 1024;
        float* bi = sc + 512;
        for (int i = tid; i < n; i += 256) {
            float s = gs[L][i] * rsqrtf(vs[L][i] + 1e-5f);
            sc[i] = s;
            bi[i] = bs[L][i] - ms[L][i] * s;
        }
    } else if (blk < 10) {
        int i = (blk - 4) * 256 + tid;
        if (i < 3 * 2 * 4 * 64) {
            int lane = i & 63;
            int t = i >> 6;
            int nf = t % 4;
            int th = t / 4;
            int h = th & 1;
            int ky = th >> 1;
            int n = nf * 16 + (lane & 15);
            int q = lane >> 4;
            u16 o8[8];
            #pragma unroll
            for (int e = 0; e < 8; ++e) {
                float v = (q < 3) ? c1w[((size_t)(n * 8 + e) * 3 + ky) * 3 + q] : 0.f;
                u16 hh = f2bf(v);
                o8[e] = (h == 0) ? hh : f2bf(v - bf2f(hh));
            }
            u16* d = bp1 + (size_t)i * 8;
            #pragma unroll
            for (int e = 0; e < 8; ++e) d[e] = o8[e];
        }
    } else if (blk < 46) {
        bpack_body(c2w, bp2, 64, 64, 9, 2, 4, (blk - 10) * 256 + tid);
    } else if (blk < 82) {
        bpack_body(c3w, bp3, 64, 64, 9, 2, 4, (blk - 46) * 256 + tid);
    } else if (blk < 262) {
        bpack_body(c4w, bp4, 64, 257, 9, 2, 20, (blk - 82) * 256 + tid);
    } else if (blk < 505) {
        bpack_body(s2w, bp5, 257, 257, 3, 9, 18, (blk - 262) * 256 + tid);
    } else {
        int row = blk - 505;
        int prow = row % 130;
        int b = row / 130;
        bool inr = (prow >= 1 && prow <= 128);
        for (int i = tid; i < 8 * 130; i += 256) {
            int c = i / 130, pcol = i % 130;
            float v = 0.f;
            if (inr && pcol >= 1 && pcol <= 128)
                v = X[(((size_t)b * 8 + c) * 128 + (prow - 1)) * 128 + (pcol - 1)];
            Xs[c][pcol] = v;
        }
        __syncthreads();
        for (int p = tid; p < 130; p += 256) {
            short8 h8, l8;
            #pragma unroll
            for (int c = 0; c < 8; ++c) {
                float f = Xs[c][p];
                u16 hh = f2bf(f);
                h8[c] = (short)hh;
                l8[c] = (short)f2bf(f - bf2f(hh));
            }
            size_t o = (((size_t)b * 130 + prow) * 130 + p) * 16;
            *(short8*)(xp + o) = h8;
            *(short8*)(xp + o + 8) = l8;
        }
    }
}

// ---------------------------------------------------------------------------
// Zero borders: generic + fused-init (c2 + c4) variants.
// ---------------------------------------------------------------------------
__device__ __forceinline__ void zpad_body(u32* buf, int Hp, int Wp, int wpp, int doCols, long idx)
{
    int perB = 2 * Wp + (doCols ? 2 * (Hp - 2) : 0);
    int w = (int)(idx % wpp);
    long t = idx / wpp;
    int p = (int)(t % perB);
    int b = (int)(t / perB);
    int row, col;
    if (p < Wp) { row = 0; col = p; }
    else if (p < 2 * Wp) { row = Hp - 1; col = p - Wp; }
    else { int pp = p - 2 * Wp; row = 1 + (pp >> 1); col = (pp & 1) ? (Wp - 1) : 0; }
    buf[(((size_t)b * Hp + row) * Wp + col) * (size_t)wpp + w] = 0;
}

__global__ __launch_bounds__(256) void zpad(
    u32* buf, int Bn, int Hp, int Wp, int wpp, int doCols)
{
    int perB = 2 * Wp + (doCols ? 2 * (Hp - 2) : 0);
    long total = (long)Bn * perB * wpp;
    for (long idx = blockIdx.x * 256L + threadIdx.x; idx < total; idx += (long)gridDim.x * 256)
        zpad_body(buf, Hp, Wp, wpp, doCols, idx);
}

__global__ __launch_bounds__(256) void zpad_init(u32* c2b, u32* c4b)
{
    const long T1 = 64L * 260 * 64;   // c2: perB = 2*66 + 2*64
    const long T2 = 64L * 68 * 64;    // c4: perB = 2*18 + 2*16
    for (long idx = blockIdx.x * 256L + threadIdx.x; idx < T1 + T2; idx += (long)gridDim.x * 256) {
        if (idx < T1) zpad_body(c2b, 66, 66, 64, 1, idx);
        else          zpad_body(c4b, 18, 18, 64, 1, idx - T1);
    }
}

// ---------------------------------------------------------------------------
// conv1 dedicated: C=8, K packs 4 pixels x 8 ch (kx in K).  3 chunks.
// Full 3-term split; term-major interleave; in-register 2x2 pooling.
// ---------------------------------------------------------------------------
__global__ __launch_bounds__(256) void conv_c1(
    const u16* __restrict__ A, const u16* __restrict__ Bp,
    const float* __restrict__ esc, const float* __restrict__ ebi,
    u16* __restrict__ O)
{
    constexpr int Wst = 130, Hp = 130;
    constexpr int SROWS = 5;                 // 2 rows + 2 halo + 1 wrap-guard
    constexpr int SPIX = SROWS * Wst;        // 650
    __shared__ __align__(16) char sm[SPIX * 48];

    int bid = blockIdx.x;
    int ytile = bid % 64;
    int b = bid / 64;
    int y0 = ytile * 2;
    int tid = threadIdx.x;
    int wv = tid >> 6;
    int l = tid & 63;
    int r = l & 15, q = l >> 4;

    #pragma unroll
    for (int it = 0; it < 3; ++it) {
        int pix = tid + it * 256;
        int prow = y0 + pix / Wst, pcol = pix % Wst;
        uint4 v0 = {0, 0, 0, 0}, v1 = {0, 0, 0, 0};
        if (pix < SPIX && prow < Hp) {
            const u16* src = A + (((size_t)b * Hp + prow) * Wst + pcol) * 16;
            v0 = *(const uint4*)src;
            v1 = *(const uint4*)(src + 8);
        }
        if (pix < SPIX) {
            *(uint4*)(sm + pix * 48) = v0;
            *(uint4*)(sm + pix * 48 + 16) = v1;
        }
    }
    __syncthreads();

    f32x4 acc[4][4] = {};

    #pragma unroll
    for (int ky = 0; ky < 3; ++ky) {
        short8 bh[4], bl[4];
        #pragma unroll
        for (int ni = 0; ni < 4; ++ni) {
            const u16* bt = Bp + ((size_t)(ky * 2) * 4 + ni) * 512 + l * 8;
            bh[ni] = *(const short8*)bt;
            bl[ni] = *(const short8*)(bt + 4 * 512);
        }
        short8 ah[4], al[4];
        #pragma unroll
        for (int mi = 0; mi < 4; ++mi) {
            int pf = wv * 2 + (mi >> 1);
            int y = mi & 1;
            int p = (y + ky) * Wst + pf * 16 + r + q;   // wrap lands on guard row, zero-weighted
            ah[mi] = *(const short8*)(sm + p * 48);
            al[mi] = *(const short8*)(sm + p * 48 + 16);
        }
        #pragma unroll
        for (int ni = 0; ni < 4; ++ni)
            #pragma unroll
            for (int mi = 0; mi < 4; ++mi)
                acc[mi][ni] = __builtin_amdgcn_mfma_f32_16x16x32_bf16(ah[mi], bh[ni], acc[mi][ni], 0, 0, 0);
        #pragma unroll
        for (int ni = 0; ni < 4; ++ni)
            #pragma unroll
            for (int mi = 0; mi < 4; ++mi)
                acc[mi][ni] = __builtin_amdgcn_mfma_f32_16x16x32_bf16(ah[mi], bl[ni], acc[mi][ni], 0, 0, 0);
        #pragma unroll
        for (int ni = 0; ni < 4; ++ni)
            #pragma unroll
            for (int mi = 0; mi < 4; ++mi)
                acc[mi][ni] = __builtin_amdgcn_mfma_f32_16x16x32_bf16(al[mi], bh[ni], acc[mi][ni], 0, 0, 0);
    }

    // in-register BN+ReLU+2x2 pool -> unified c2 (66x66, 2 sections)
    #pragma unroll
    for (int ni = 0; ni < 4; ++ni) {
        int oc = ni * 16 + r;
        float sc0 = esc[oc], bi0 = ebi[oc];
        #pragma unroll
        for (int pi = 0; pi < 2; ++pi) {
            int pf = wv * 2 + pi;
            #pragma unroll
            for (int k = 0; k < 2; ++k) {
                float m = -3.4e38f;
                #pragma unroll
                for (int dmi = 0; dmi < 2; ++dmi)
                    #pragma unroll
                    for (int dj = 0; dj < 2; ++dj)
                        m = fmaxf(m, fmaf(acc[2 * pi + dmi][ni][2 * k + dj], sc0, bi0));
                m = fmaxf(m, 0.f);
                int x2 = pf * 8 + q * 2 + k;
                size_t base = (((size_t)b * 66 + (y0 / 2 + 1)) * 66 + (x2 + 1)) * 128;
                u16* d = O + base + ((oc >> 5) << 6) + (oc & 31);
                u16 hh = f2bf(m);
                d[0] = hh;
                d[32] = f2bf(m - bf2f(hh));
            }
        }
    }
}

// ---------------------------------------------------------------------------
// Shift-GEMM conv (C=64) via MFMA bf16 3-term split.  Unified layout, CSECT=2,
// XOR-swizzled LDS, direct dual-load staging, B prefetch, term-major.
// OUTMODE 0: BN+ReLU+pool2 -> unified NHWC;  OUTMODE 1: -> f32 NHWC
// ---------------------------------------------------------------------------
template<int H, int W, int OC, int R, int NF, int MFW, int OUTMODE, int NFTOT>
__global__ __launch_bounds__(256) void conv_gemm(
    const u16* __restrict__ A, const u16* __restrict__ Bp,
    const float* __restrict__ esc, const float* __restrict__ ebi,
    u16* __restrict__ O, float* __restrict__ Of)
{
    constexpr int Wst = W + 2, Hp = H + 2;
    constexpr int SROWS = R + 2;
    constexpr int SPIX = SROWS * Wst;
    constexpr int XF = W / 16;
    constexpr int HT = H / R;
    constexpr int GR = SPIX * 4;              // 32-B granules per phase
    constexpr int ROUNDS = (GR + 255) / 256;
    __shared__ __align__(16) char sm[SPIX * 128];

    int bid = blockIdx.x;
    int ytile = bid % HT;
    int b = bid / HT;
    int tid = threadIdx.x;
    int wv = tid >> 6;
    int l = tid & 63;
    int r = l & 15, q = l >> 4;
    int y0 = ytile * R;
    int nfg0 = blockIdx.y * NF;

    f32x4 acc[MFW][NF] = {};
    short8 Bh[2][NF], Bl[2][NF];

    auto loadB = [&](int buf, int chunk) {
        #pragma unroll
        for (int ni = 0; ni < NF; ++ni) {
            const u16* bt = Bp + ((size_t)(chunk * 2) * NFTOT + nfg0 + ni) * 512 + l * 8;
            Bh[buf][ni] = *(const short8*)bt;
            Bl[buf][ni] = *(const short8*)(bt + (size_t)NFTOT * 512);
        }
    };

    auto stage = [&](int cs) {
        #pragma unroll
        for (int it = 0; it < ROUNDS; ++it) {
            int idx = tid + it * 256;
            int pix = idx >> 2, sub = idx & 3;
            int prow = y0 + pix / Wst, pcol = pix % Wst;
            uint4 v0 = {0, 0, 0, 0}, v1 = {0, 0, 0, 0};
            if (idx < GR && prow < Hp) {
                const u16* src = A + (((size_t)b * Hp + prow) * Wst + pcol) * 128 + cs * 64 + sub * 8;
                v0 = *(const uint4*)src;
                v1 = *(const uint4*)(src + 32);
            }
            if (idx < GR) {
                *(uint4*)(sm + pix * 128 + ((sub ^ (pix & 7)) << 4)) = v0;
                *(uint4*)(sm + pix * 128 + (((sub + 4) ^ (pix & 7)) << 4)) = v1;
            }
        }
    };

    auto computePhase = [&](auto csc) {
        constexpr int cs = decltype(csc)::value;
        #pragma unroll
        for (int s = 0; s < 9; ++s) {
            int cur = (cs * 9 + s) & 1;            // compile-time (unrolled)
            if (s < 8) loadB(cur ^ 1, (s + 1) * 2 + cs);
            else if (cs == 0) loadB(cur ^ 1, 1);   // s=0 of section 1
            int ky = s / 3, kx = s % 3;
            short8 ah[MFW], al[MFW];
            #pragma unroll
            for (int mi = 0; mi < MFW; ++mi) {
                int pf = wv * (MFW / 2) + (mi >> 1);
                int y = (pf / XF) * 2 + (mi & 1);
                int xf = pf % XF;
                int p = (y + ky) * Wst + xf * 16 + kx + r;
                int off = p * 128 + ((q ^ (p & 7)) << 4);
                ah[mi] = *(const short8*)(sm + off);
                al[mi] = *(const short8*)(sm + (off ^ 64));
            }
            // term-major: NF*MFW independent MFMAs between dependent uses
            #pragma unroll
            for (int ni = 0; ni < NF; ++ni)
                #pragma unroll
                for (int mi = 0; mi < MFW; ++mi)
                    acc[mi][ni] = __builtin_amdgcn_mfma_f32_16x16x32_bf16(ah[mi], Bh[cur][ni], acc[mi][ni], 0, 0, 0);
            #pragma unroll
            for (int ni = 0; ni < NF; ++ni)
                #pragma unroll
                for (int mi = 0; mi < MFW; ++mi)
                    acc[mi][ni] = __builtin_amdgcn_mfma_f32_16x16x32_bf16(ah[mi], Bl[cur][ni], acc[mi][ni], 0, 0, 0);
            #pragma unroll
            for (int ni = 0; ni < NF; ++ni)
                #pragma unroll
                for (int mi = 0; mi < MFW; ++mi)
                    acc[mi][ni] = __builtin_amdgcn_mfma_f32_16x16x32_bf16(al[mi], Bh[cur][ni], acc[mi][ni], 0, 0, 0);
        }
    };

    stage(0);
    loadB(0, 0);   // chunk = s*2+cs
    __syncthreads();
    computePhase(IC<0>{});
    __syncthreads();
    stage(1);
    __syncthreads();
    computePhase(IC<1>{});

    // in-register BN+ReLU+2x2 pool epilogue
    #pragma unroll
    for (int ni = 0; ni < NF; ++ni) {
        int oc = (nfg0 + ni) * 16 + r;
        float sc0 = esc[oc], bi0 = ebi[oc];   // bns regions 512-padded: safe oc<320
        #pragma unroll
        for (int pi = 0; pi < MFW / 2; ++pi) {
            int pf = wv * (MFW / 2) + pi;
            int y2 = y0 / 2 + pf / XF;
            int xb = (pf % XF) * 8 + q * 2;
            #pragma unroll
            for (int k = 0; k < 2; ++k) {
                float m = -3.4e38f;
                #pragma unroll
                for (int dmi = 0; dmi < 2; ++dmi)
                    #pragma unroll
                    for (int dj = 0; dj < 2; ++dj)
                        m = fmaxf(m, fmaf(acc[2 * pi + dmi][ni][2 * k + dj], sc0, bi0));
                m = fmaxf(m, 0.f);
                int x2 = xb + k;
                if (OUTMODE == 0) {
                    size_t base = (((size_t)b * (H / 2 + 2) + y2 + 1) * (W / 2 + 2) + (x2 + 1)) * 128;
                    u16* d = O + base + ((oc >> 5) << 6) + (oc & 31);
                    u16 hh = f2bf(m);
                    d[0] = hh;
                    d[32] = f2bf(m - bf2f(hh));
                } else {
                    if (oc < OC)
                        Of[(((size_t)b * (H / 2) + y2) * (W / 2) + x2) * (size_t)OC + oc] = m;
                }
            }
        }
    }
}

// ---------------------------------------------------------------------------
// convs2 GEMM, t-split x3 (128 t/block), direct staging, term-major (3-term),
// FUSED attention partial sums -> part[b][3][257].
// A: mu unified (b,362,9x128B).  Out sp2 (b,360,257) f32.
// ---------------------------------------------------------------------------
__global__ __launch_bounds__(256) void convs2_gemm(
    const u16* __restrict__ A, const u16* __restrict__ Bp,
    const float* __restrict__ bia, float* __restrict__ sp2,
    float* __restrict__ part)
{
    constexpr int SPIX = 130;
    constexpr int GR = SPIX * 4;     // 520
    __shared__ __align__(16) char sm[SPIX * 128];

    int bid = blockIdx.x;
    int tt = bid % 3;
    int b = bid / 3;
    int nt = blockIdx.y;
    int t0 = tt * 128;
    int tid = threadIdx.x;
    int wv = tid >> 6;
    int l = tid & 63;
    int r = l & 15, q = l >> 4;

    f32x4 acc[2][3] = {};
    short8 Bh[2][3], Bl[2][3];

    auto loadB = [&](int buf, int chunk) {
        #pragma unroll
        for (int ni = 0; ni < 3; ++ni) {
            const u16* bt = Bp + ((size_t)(chunk * 2) * 18 + nt * 3 + ni) * 512 + l * 8;
            Bh[buf][ni] = *(const short8*)bt;
            Bl[buf][ni] = *(const short8*)(bt + 18 * 512);
        }
    };

    auto stage = [&](int cs) {
        #pragma unroll
        for (int it = 0; it < 3; ++it) {
            int idx = tid + it * 256;
            int pix = idx >> 2, sub = idx & 3;
            int gp = t0 + pix;
            uint4 v0 = {0, 0, 0, 0}, v1 = {0, 0, 0, 0};
            if (idx < GR && gp < 362) {
                const u16* src = A + ((size_t)b * 362 + gp) * 576 + cs * 64 + sub * 8;
                v0 = *(const uint4*)src;
                v1 = *(const uint4*)(src + 32);
            }
            if (idx < GR) {
                *(uint4*)(sm + pix * 128 + ((sub ^ (pix & 7)) << 4)) = v0;
                *(uint4*)(sm + pix * 128 + (((sub + 4) ^ (pix & 7)) << 4)) = v1;
            }
        }
    };

    stage(0);
    loadB(0, 0);   // chunk = ky*9 + cs
    __syncthreads();

    #pragma unroll
    for (int cs = 0; cs < 9; ++cs) {
        #pragma unroll
        for (int ky = 0; ky < 3; ++ky) {
            int cur = (cs * 3 + ky) & 1;       // compile-time (unrolled)
            if (ky < 2) loadB(cur ^ 1, (ky + 1) * 9 + cs);
            else if (cs < 8) loadB(cur ^ 1, cs + 1);
            short8 ah[2], al[2];
            #pragma unroll
            for (int mi = 0; mi < 2; ++mi) {
                int p = (wv * 2 + mi) * 16 + r + ky;
                int off = p * 128 + ((q ^ (p & 7)) << 4);
                ah[mi] = *(const short8*)(sm + off);
                al[mi] = *(const short8*)(sm + (off ^ 64));
            }
            // term-major: 6 independent MFMAs between dependent uses
            #pragma unroll
            for (int ni = 0; ni < 3; ++ni)
                #pragma unroll
                for (int mi = 0; mi < 2; ++mi)
                    acc[mi][ni] = __builtin_amdgcn_mfma_f32_16x16x32_bf16(ah[mi], Bh[cur][ni], acc[mi][ni], 0, 0, 0);
            #pragma unroll
            for (int ni = 0; ni < 3; ++ni)
                #pragma unroll
                for (int mi = 0; mi < 2; ++mi)
                    acc[mi][ni] = __builtin_amdgcn_mfma_f32_16x16x32_bf16(ah[mi], Bl[cur][ni], acc[mi][ni], 0, 0, 0);
            #pragma unroll
            for (int ni = 0; ni < 3; ++ni)
                #pragma unroll
                for (int mi = 0; mi < 2; ++mi)
                    acc[mi][ni] = __builtin_amdgcn_mfma_f32_16x16x32_bf16(al[mi], Bh[cur][ni], acc[mi][ni], 0, 0, 0);
        }
        __syncthreads();
        if (cs < 8) {
            stage(cs + 1);
            __syncthreads();
        }
    }

    // epilogue: bias + leaky store, accumulating per-thread t-partials
    float psum[3] = {0.f, 0.f, 0.f};
    #pragma unroll
    for (int ni = 0; ni < 3; ++ni) {
        int n = (nt * 3 + ni) * 16 + r;
        if (n >= NFB) continue;
        float bi0 = bia[n];
        #pragma unroll
        for (int mi = 0; mi < 2; ++mi) {
            int tb = t0 + (wv * 2 + mi) * 16 + q * 4;
            #pragma unroll
            for (int j = 0; j < 4; ++j) {
                int t = tb + j;
                if (t < NANG) {
                    float v = acc[mi][ni][j] + bi0;
                    v = (v >= 0.f) ? v : 0.1f * v;
                    sp2[((size_t)b * NANG + t) * NFB + n] = v;
                    psum[ni] += v;
                }
            }
        }
    }
    // reduce psum over q (shfl) then over waves (LDS), write part[b][tt][f]
    float* wred = (float*)sm;                 // 4 waves x 3 ni x 16 r
    #pragma unroll
    for (int ni = 0; ni < 3; ++ni) {
        float s = psum[ni];
        s += __shfl_down(s, 32, 64);
        s += __shfl_down(s, 16, 64);
        if (q == 0) wred[(wv * 3 + ni) * 16 + r] = s;
    }
    __syncthreads();
    if (tid < 48) {
        int ni = tid / 16, rr = tid % 16;
        float tot = wred[(0 * 3 + ni) * 16 + rr] + wred[(1 * 3 + ni) * 16 + rr]
                  + wred[(2 * 3 + ni) * 16 + rr] + wred[(3 * 3 + ni) * 16 + rr];
        int n = (nt * 3 + ni) * 16 + rr;
        if (n < NFB) part[((size_t)b * 3 + tt) * NFB + n] = tot;
    }
}

// ---------------------------------------------------------------------------
// FC: z (b, 64 pix, 257 f) NHWC f32 -> zfc (b, f, 32)
// ---------------------------------------------------------------------------
__global__ __launch_bounds__(256) void fc_kernel(
    const float* __restrict__ z, const float* __restrict__ fw,
    const float* __restrict__ fb, float* __restrict__ zfc)
{
    int bid = blockIdx.x;
    int ftile = bid % 33;
    int b = bid / 33;
    int j = threadIdx.x & 31;
    int f = ftile * 8 + (threadIdx.x >> 5);
    if (f >= 257) return;
    const float* zb = z + (size_t)b * 16448;
    float a = fb[j];
    #pragma unroll 8
    for (int s = 0; s < 64; ++s) a = fmaf(zb[s * 257 + f], fw[j * 64 + s], a);
    zfc[((size_t)b * 257 + f) * 32 + j] = a;
}

// ---------------------------------------------------------------------------
// Per-thread 4x4 Hermitian eigh (complex Jacobi, f64) -> Re(Un Un^H)
// 256-thread blocks for wave packing (identical per-thread math).
// ---------------------------------------------------------------------------
__global__ __launch_bounds__(256) void eigh_kernel(const float* __restrict__ z, double* __restrict__ rp)
{
    int idx = blockIdx.x * 256 + threadIdx.x;
    if (idx >= NB * NFB) return;
    const float* zr = z + (size_t)idx * 32;
    double Ar[4][4], Ai[4][4], Vr[4][4], Vi[4][4];
    #pragma unroll
    for (int m = 0; m < 4; ++m)
        #pragma unroll
        for (int n = 0; n < 4; ++n) {
            Ar[m][n] = 0.5 * ((double)zr[m * 8 + n] + (double)zr[n * 8 + m]);
            Ai[m][n] = 0.5 * ((double)zr[m * 8 + n + 4] - (double)zr[n * 8 + m + 4]);
            Vr[m][n] = (m == n) ? 1.0 : 0.0;
            Vi[m][n] = 0.0;
        }
    #pragma unroll
    for (int m = 0; m < 4; ++m) Ar[m][m] += 1e-5;

    for (int sweep = 0; sweep < 8; ++sweep) {
        #pragma unroll
        for (int p = 0; p < 3; ++p)
            #pragma unroll
            for (int qq = p + 1; qq < 4; ++qq) {
                double apr = Ar[p][qq], api = Ai[p][qq];
                double rmod = sqrt(apr * apr + api * api);
                if (rmod < 1e-300) continue;
                double cph = apr / rmod, sph = api / rmod;
                double tau = (Ar[qq][qq] - Ar[p][p]) / (2.0 * rmod);
                double t = (tau >= 0.0) ? (-1.0 / (tau + sqrt(1.0 + tau * tau)))
                                        : (1.0 / (-tau + sqrt(1.0 + tau * tau)));
                double c = 1.0 / sqrt(1.0 + t * t);
                double s = t * c;
                double wr = s * cph, wi = s * sph;
                #pragma unroll
                for (int i = 0; i < 4; ++i) {
                    double xr = Ar[i][p], xi = Ai[i][p];
                    double yr = Ar[i][qq], yi = Ai[i][qq];
                    Ar[i][p] = c * xr + (wr * yr + wi * yi);
                    Ai[i][p] = c * xi + (wr * yi - wi * yr);
                    Ar[i][qq] = c * yr - (wr * xr - wi * xi);
                    Ai[i][qq] = c * yi - (wr * xi + wi * xr);
                }
                #pragma unroll
                for (int i = 0; i < 4; ++i) {
                    double xr = Ar[p][i], xi = Ai[p][i];
                    double yr = Ar[qq][i], yi = Ai[qq][i];
                    Ar[p][i] = c * xr + (wr * yr - wi * yi);
                    Ai[p][i] = c * xi + (wr * yi + wi * yr);
                    Ar[qq][i] = c * yr - (wr * xr + wi * xi);
                    Ai[qq][i] = c * yi - (wr * xi - wi * xr);
                }
                #pragma unroll
                for (int i = 0; i < 4; ++i) {
                    double xr = Vr[i][p], xi = Vi[i][p];
                    double yr = Vr[i][qq], yi = Vi[i][qq];
                    Vr[i][p] = c * xr + (wr * yr + wi * yi);
                    Vi[i][p] = c * xi + (wr * yi - wi * yr);
                    Vr[i][qq] = c * yr - (wr * xr - wi * xi);
                    Vi[i][qq] = c * yi - (wr * xi + wi * xr);
                }
            }
    }
    double ev[4] = {Ar[0][0], Ar[1][1], Ar[2][2], Ar[3][3]};
    int i0 = 0;
    #pragma unroll
    for (int k = 1; k < 4; ++k) if (ev[k] < ev[i0]) i0 = k;
    int i1 = (i0 == 0) ? 1 : 0;
    #pragma unroll
    for (int k = 0; k < 4; ++k) if (k != i0 && ev[k] < ev[i1]) i1 = k;
    double* o = rp + (size_t)idx * 16;
    #pragma unroll
    for (int m = 0; m < 4; ++m)
        #pragma unroll
        for (int n = 0; n < 4; ++n)
            o[m * 4 + n] = Vr[m][i0] * Vr[n][i0] + Vi[m][i0] * Vi[n][i0]
                         + Vr[m][i1] * Vr[n][i1] + Vi[m][i1] * Vi[n][i1];
}

// ---------------------------------------------------------------------------
// MUSIC spectrum -> unified mu (b, t=a+1 in 362, 9 sections of [hi32|lo32]).
// 64-angle blocks, 8 bins/thread (16 loads in flight), symmetric 10-term
// form in f64, final reciprocal in f32.
// ---------------------------------------------------------------------------
__global__ __launch_bounds__(256) void music_kernel(
    const float4* __restrict__ svr, const float4* __restrict__ svi,
    const double* __restrict__ rp, u16* __restrict__ mu)
{
    __shared__ double P[32][10];
    __shared__ float T[64][33];
    int bid = blockIdx.x;
    int at = bid % 6; bid /= 6;     // 6 at-tiles of 64 angles
    int ft = bid % 9;
    int b = bid / 9;
    int f0 = ft * 32, a0 = at * 64;
    int tid = threadIdx.x;
    // stage P compressed: j -> (m,n) pairs; off-diag doubled
    for (int i = tid; i < 32 * 10; i += 256) {
        int fi = i / 10, j = i % 10;
        const int mm[10] = {0, 1, 2, 3, 0, 0, 0, 1, 1, 2};
        const int nn[10] = {0, 1, 2, 3, 1, 2, 3, 2, 3, 3};
        int f = f0 + fi;
        double v = 0.0;
        if (f < 257) {
            v = rp[((size_t)b * 257 + f) * 16 + mm[j] * 4 + nn[j]];
            if (j >= 4) v += v;
        }
        P[fi][j] = v;
    }
    __syncthreads();
    int asub = tid & 63, fsub = tid >> 6;   // fsub 0..3
    int a = a0 + asub;
    bool av = (a < 360);
    // prefetch ALL loads (16 independent) before any f64 compute
    float4 u[8], w[8];
    #pragma unroll
    for (int k2 = 0; k2 < 8; ++k2) {
        int f = f0 + fsub * 8 + k2;
        u[k2] = (float4){0.f, 0.f, 0.f, 0.f};
        w[k2] = (float4){0.f, 0.f, 0.f, 0.f};
        if (av && f < 257) {
            u[k2] = svr[((size_t)b * 257 + f) * 360 + a];
            w[k2] = svi[((size_t)b * 257 + f) * 360 + a];
        }
    }
    #pragma unroll
    for (int k2 = 0; k2 < 8; ++k2) {
        int fl = fsub * 8 + k2;
        double ua[4] = {u[k2].x, u[k2].y, u[k2].z, u[k2].w};
        double wa[4] = {w[k2].x, w[k2].y, w[k2].z, w[k2].w};
        const double* Pf = P[fl];
        const int mm[10] = {0, 1, 2, 3, 0, 0, 0, 1, 1, 2};
        const int nn[10] = {0, 1, 2, 3, 1, 2, 3, 2, 3, 3};
        double den = 0.0;
        #pragma unroll
        for (int j = 0; j < 10; ++j)
            den += Pf[j] * (ua[mm[j]] * ua[nn[j]] - wa[mm[j]] * wa[nn[j]]);
        float denf = (float)fmax(den, 1e-6);
        T[asub][fl] = 1.0f / denf;
    }
    __syncthreads();
    int sec0 = f0 >> 5;
    #pragma unroll
    for (int p = 0; p < 8; ++p) {
        int row = p * 8 + (tid >> 5);
        int fc = tid & 31;
        int a2 = a0 + row;
        if (a2 < 360) {
            float v = T[row][fc];
            u16* d = mu + ((size_t)b * 362 + a2 + 1) * 576 + (size_t)sec0 * 64 + fc;
            u16 hh = f2bf(v);
            d[0] = hh;
            d[32] = f2bf(v - bf2f(hh));
        }
    }
}

// ---------------------------------------------------------------------------
// attention finish (mean -> MLP -> sigmoid); part has 3 chunks per b.
// h-dot parallelized: 16 h x 16 threads.
// ---------------------------------------------------------------------------
__global__ __launch_bounds__(256) void attn_finish(
    const float* __restrict__ part, const float* __restrict__ w1,
    const float* __restrict__ w2, float* __restrict__ att)
{
    __shared__ float ys[257];
    __shared__ float hp[16][17];
    __shared__ float hs[16];
    int b = blockIdx.x;
    int tid = threadIdx.x;
    for (int f = tid; f < 257; f += 256) {
        float s = part[((size_t)b * 3 + 0) * 257 + f]
                + part[((size_t)b * 3 + 1) * 257 + f]
                + part[((size_t)b * 3 + 2) * 257 + f];
        ys[f] = s * (1.0f / 360.0f);
    }
    __syncthreads();
    {
        int h = tid >> 4, seg = tid & 15;
        float p = 0.f;
        for (int c = seg; c < 257; c += 16)
            p = fmaf(ys[c], w1[(size_t)h * 257 + c], p);
        hp[h][seg] = p;
    }
    __syncthreads();
    if (tid < 16) {
        float s = 0.f;
        #pragma unroll
        for (int k = 0; k < 16; ++k) s += hp[tid][k];
        hs[tid] = fmaxf(s, 0.f);
    }
    __syncthreads();
    for (int o = tid; o < 257; o += 256) {
        float a = 0.f;
        #pragma unroll
        for (int j = 0; j < 16; ++j) a = fmaf(hs[j], w2[(size_t)o * 16 + j], a);
        att[(size_t)b * 257 + o] = 1.0f / (1.0f + expf(-a));
    }
}

// ---------------------------------------------------------------------------
// conv1d 257->1 over att-weighted sp2(b,t,f), sigmoid -> outS (b,360)
// ---------------------------------------------------------------------------
__global__ __launch_bounds__(256) void convs1_kernel(
    const float* __restrict__ sp2, const float* __restrict__ att,
    const float* __restrict__ w, const float* __restrict__ bb,
    float* __restrict__ outS)
{
    int bid = blockIdx.x;
    int tt = bid % 90;
    int b = bid / 90;
    int wv = threadIdx.x >> 6, l = threadIdx.x & 63;
    int t = tt * 4 + wv;
    float s = 0.f;
    for (int f = l; f < 257; f += 64) {
        float av = att[(size_t)b * 257 + f];
        float w0 = w[f * 3] * av, w1 = w[f * 3 + 1] * av, w2 = w[f * 3 + 2] * av;
        const float* col = sp2 + (size_t)b * 360 * 257 + f;
        if (t > 0)   s = fmaf(w0, col[(size_t)(t - 1) * 257], s);
        s = fmaf(w1, col[(size_t)t * 257], s);
        if (t < 359) s = fmaf(w2, col[(size_t)(t + 1) * 257], s);
    }
    #pragma unroll
    for (int off = 32; off > 0; off >>= 1) s += __shfl_down(s, off, 64);
    if (l == 0) outS[(size_t)b * 360 + t] = 1.0f / (1.0f + expf(-(s + bb[0])));
}

// ---------------------------------------------------------------------------
// top-5 soft-argmax, wave-parallel (strict >, index asc tie-break)
// ---------------------------------------------------------------------------
__global__ __launch_bounds__(64) void doa_kernel(const float* __restrict__ spec, float* __restrict__ doa)
{
    int b = blockIdx.x;
    int l = threadIdx.x;
    const float* s = spec + (size_t)b * NANG;
    float v[6];
    #pragma unroll
    for (int j = 0; j < 6; ++j) {
        int idx = l + 64 * j;
        v[j] = (idx < NANG) ? s[idx] : -3.4e38f;
    }
    float wvv[5]; int wii[5];
    #pragma unroll
    for (int k = 0; k < 5; ++k) {
        float bv = v[0]; int bj = 0;
        #pragma unroll
        for (int j = 1; j < 6; ++j)
            if (v[j] > bv) { bv = v[j]; bj = j; }
        int bi = l + 64 * bj;
        #pragma unroll
        for (int off = 1; off < 64; off <<= 1) {
            float ov = __shfl_xor(bv, off, 64);
            int oi = __shfl_xor(bi, off, 64);
            if (ov > bv || (ov == bv && oi < bi)) { bv = ov; bi = oi; }
        }
        wvv[k] = bv; wii[k] = bi;
        if ((bi & 63) == l) {
            int j = bi >> 6;
            #pragma unroll
            for (int jj = 0; jj < 6; ++jj)
                if (jj == j) v[jj] = -3.4e38f;
        }
    }
    if (l == 0) {
        float m = wvv[0];
        float wsum = 0.f, asum = 0.f;
        #pragma unroll
        for (int k = 0; k < 5; ++k) {
            float e = expf(20.0f * (wvv[k] - m));
            wsum += e;
            asum += e * (float)wii[k];
        }
        doa[b] = asum / wsum;
    }
}

// ---------------------------------------------------------------------------
extern "C" void kernel_launch(void* const* d_in, const int* in_sizes, int n_in,
                              void* d_out, int out_size, void* d_ws, size_t ws_size,
                              hipStream_t stream)
{
    const float* X    = (const float*)d_in[0];
    const float* svr  = (const float*)d_in[1];
    const float* svi  = (const float*)d_in[2];
    const float* c1w  = (const float*)d_in[4];
    const float* c2w  = (const float*)d_in[5];
    const float* c3w  = (const float*)d_in[6];
    const float* c4w  = (const float*)d_in[7];
    const float* fcw  = (const float*)d_in[8];
    const float* fcb  = (const float*)d_in[9];
    const float* s2w  = (const float*)d_in[10];
    const float* s2b  = (const float*)d_in[11];
    const float* s1w  = (const float*)d_in[12];
    const float* s1b  = (const float*)d_in[13];
    const float* caw1 = (const float*)d_in[14];
    const float* caw2 = (const float*)d_in[15];
    const float* bn1g = (const float*)d_in[16]; const float* bn1b = (const float*)d_in[17];
    const float* bn1m = (const float*)d_in[18]; const float* bn1v = (const float*)d_in[19];
    const float* bn2g = (const float*)d_in[20]; const float* bn2b = (const float*)d_in[21];
    const float* bn2m = (const float*)d_in[22]; const float* bn2v = (const float*)d_in[23];
    const float* bn3g = (const float*)d_in[24]; const float* bn3b = (const float*)d_in[25];
    const float* bn3m = (const float*)d_in[26]; const float* bn3v = (const float*)d_in[27];
    const float* bn4g = (const float*)d_in[28]; const float* bn4b = (const float*)d_in[29];
    const float* bn4m = (const float*)d_in[30]; const float* bn4v = (const float*)d_in[31];

    char* wsb = (char*)d_ws;
    // region A (time-disjoint: xp -> c3 -> mu)
    u16* xp = (u16*)(wsb + 0);               // 34,611,200 B (64x130x130x32B)
    u16* c3 = (u16*)(wsb + 0);               // 18,939,904 B (64x34x34x256B)
    u16* mu = (u16*)(wsb + 0);               // 26,689,536 B (64x362x1152B)
    // region B (c2 -> {zbuf, zfc, rp, sp2, part, att})
    const size_t Bb = 34611200;
    u16*   c2  = (u16*)(wsb + Bb);           // 71,368,704 B (64x66x66x256B)
    float*  zbuf = (float*)(wsb + Bb);
    float*  zfc  = (float*)(wsb + Bb + 4210688);
    double* rp   = (double*)(wsb + Bb + 6316032);
    float*  sp2  = (float*)(wsb + Bb + 8421376);
    float*  part = (float*)(wsb + Bb + 32106496);
    float*  att  = (float*)(wsb + Bb + 32501248);
    // region C (persistent small)
    const size_t Cb = Bb + 71368704;
    u16* c4  = (u16*)(wsb + Cb);             // 5,308,416 B (64x18x18x256B)
    u16* bp1 = (u16*)(wsb + Cb + 5308416);
    u16* bp2 = (u16*)(wsb + Cb + 5382144);
    u16* bp3 = (u16*)(wsb + Cb + 5529600);
    u16* bp4 = (u16*)(wsb + Cb + 5677056);
    u16* bp5 = (u16*)(wsb + Cb + 6414336);
    float* bns = (float*)(wsb + Cb + 7409664);

    float* outD = (float*)d_out;
    float* outS = (float*)d_out + 64;

    // --- fused prep (bnprep + all bpacks + xpack) + fused init zpads ---
    prep_kernel<<<8825, 256, 0, stream>>>(
        X, xp, c1w, bp1, c2w, bp2, c3w, bp3, c4w, bp4, s2w, bp5,
        bn1g, bn1b, bn1m, bn1v, bn2g, bn2b, bn2m, bn2v,
        bn3g, bn3b, bn3m, bn3v, bn4g, bn4b, bn4m, bn4v, bns);
    zpad_init<<<2048, 256, 0, stream>>>((u32*)c2, (u32*)c4);

    // --- conv1 (3-term) ---
    conv_c1<<<64 * 64, 256, 0, stream>>>(xp, bp1, bns, bns + 512, c2);
    zpad<<<2112, 256, 0, stream>>>((u32*)c3, 64, 34, 34, 64, 1);   // A region free now
    // --- conv2 (3-term) ---
    conv_gemm<64, 64, 64, 2, 4, 2, 0, 4>
        <<<dim3(64 * 32, 1), 256, 0, stream>>>(c2, bp2, bns + 1024, bns + 1536, c3, nullptr);
    // --- conv3 (3-term) ---
    conv_gemm<32, 32, 64, 4, 4, 2, 0, 4>
        <<<dim3(64 * 8, 1), 256, 0, stream>>>(c3, bp3, bns + 2048, bns + 2560, c4, nullptr);
    zpad<<<144, 256, 0, stream>>>((u32*)mu, 64, 362, 1, 288, 0);   // A region free now
    // --- conv4 (3-term) -> z f32 (b,8,8,257) ---
    conv_gemm<16, 16, 257, 8, 4, 2, 1, 20>
        <<<dim3(64 * 2, 5), 256, 0, stream>>>(c4, bp4, bns + 3072, bns + 3584, nullptr, zbuf);

    fc_kernel<<<64 * 33, 256, 0, stream>>>(zbuf, fcw, fcb, zfc);
    eigh_kernel<<<65, 256, 0, stream>>>(zfc, rp);
    music_kernel<<<64 * 54, 256, 0, stream>>>((const float4*)svr, (const float4*)svi, rp, mu);
    // --- convs2 (3-term, +fused attention partial sums) -> sp2, part ---
    convs2_gemm<<<dim3(64 * 3, 6), 256, 0, stream>>>(mu, bp5, s2b, sp2, part);

    attn_finish<<<64, 256, 0, stream>>>(part, caw1, caw2, att);
    convs1_kernel<<<64 * 90, 256, 0, stream>>>(sp2, att, s1w, s1b, outS);
    doa_kernel<<<64, 64, 0, stream>>>(outS, outD);
}

// Round 14
// 379.715 us; speedup vs baseline: 1.0437x; 1.0437x over previous
//
#include <hip/hip_runtime.h>

typedef unsigned short u16;
typedef unsigned int u32;
typedef short short8 __attribute__((ext_vector_type(8)));
typedef float f32x4 __attribute__((ext_vector_type(4)));

#define NB 64
#define NFB 257
#define NANG 360

template<int V> struct IC { static constexpr int value = V; };

__device__ __forceinline__ u16 f2bf(float x) {
    u32 u = __float_as_uint(x);
    u = (u + 0x7fffu + ((u >> 16) & 1u)) >> 16;
    return (u16)u;
}
__device__ __forceinline__ float bf2f(u16 h) { return __uint_as_float(((u32)h) << 16); }

// ---------------------------------------------------------------------------
// Unified activation layout: per pixel, (C/32) sections of 128 B:
//   [hi ch0-31 (64B) | lo ch0-31 (64B)] [hi ch32-63 | lo ch32-63] ...
// NUMERICS NOTE (round-10 failure): all convs must keep the full 3-term
// bf16 split (Ah*Bh + Ah*Bl + Al*Bh ~ f32 quality).  2-term (B rounded to
// bf16) produced 0.2%/layer error that flipped near-degenerate eigenvector
// subspaces in eigh -> 1/denom chaos -> doa absmax 171.  Do not retry.
// PERF NOTE (rounds 12/13): music is occupancy/latency-bound.  8-load
// prefetch @ VGPR 40 / 56% occ is the local optimum; 16-load prefetch
// (VGPR 76, 28% occ) REGRESSED 69.5 -> 83 us.  Do not deepen prefetch.
// ---------------------------------------------------------------------------

// ---------------------------------------------------------------------------
// Fused prep: bnprep(4) | bpack1(6) | bpack c2(36) c3(36) c4(180) s2(243) |
// xpack(8320).  One launch, branch by block range.
// ---------------------------------------------------------------------------
__device__ __forceinline__ void bpack_body(
    const float* __restrict__ w, u16* __restrict__ Bp,
    int CREAL, int OCREAL, int NT, int KCC, int NFTOT, int i)
{
    int total = NT * KCC * 2 * NFTOT * 64;
    if (i >= total) return;
    int lane = i & 63;
    int t = i >> 6;
    int nf = t % NFTOT;
    int th = t / NFTOT;
    int h = th & 1;
    int chunk = th >> 1;
    int s = chunk / KCC, kc = chunk % KCC;
    int n = nf * 16 + (lane & 15);
    int k0 = kc * 32 + (lane >> 4) * 8;
    u16 o8[8];
    #pragma unroll
    for (int e = 0; e < 8; ++e) {
        int k = k0 + e;
        float v = 0.f;
        if (k < CREAL && n < OCREAL) v = w[((size_t)n * CREAL + k) * NT + s];
        u16 hh = f2bf(v);
        o8[e] = (h == 0) ? hh : f2bf(v - bf2f(hh));
    }
    u16* d = Bp + (size_t)i * 8;
    #pragma unroll
    for (int e = 0; e < 8; ++e) d[e] = o8[e];
}

__global__ __launch_bounds__(256) void prep_kernel(
    const float* __restrict__ X, u16* __restrict__ xp,
    const float* __restrict__ c1w, u16* __restrict__ bp1,
    const float* __restrict__ c2w, u16* __restrict__ bp2,
    const float* __restrict__ c3w, u16* __restrict__ bp3,
    const float* __restrict__ c4w, u16* __restrict__ bp4,
    const float* __restrict__ s2w, u16* __restrict__ bp5,
    const float* g1, const float* b1, const float* m1, const float* v1,
    const float* g2, const float* b2, const float* m2, const float* v2,
    const float* g3, const float* b3, const float* m3, const float* v3,
    const float* g4, const float* b4, const float* m4, const float* v4,
    float* __restrict__ bns)
{
    __shared__ float Xs[8][132];
    int blk = blockIdx.x;
    int tid = threadIdx.x;
    if (blk < 4) {
        int L = blk;
        const float* gs[4] = {g1, g2, g3, g4};
        const float* bs[4] = {b1, b2, b3, b4};
        const float* ms[4] = {m1, m2, m3, m4};
        const float* vs[4] = {v1, v2, v3, v4};
        int n = (L == 3) ? 257 : 64;
        float* sc = bns + L * 1024;
        float* bi = sc + 512;
        for (int i = tid; i < n; i += 256) {
            float s = gs[L][i] * rsqrtf(vs[L][i] + 1e-5f);
            sc[i] = s;
            bi[i] = bs[L][i] - ms[L][i] * s;
        }
    } else if (blk < 10) {
        int i = (blk - 4) * 256 + tid;
        if (i < 3 * 2 * 4 * 64) {
            int lane = i & 63;
            int t = i >> 6;
            int nf = t % 4;
            int th = t / 4;
            int h = th & 1;
            int ky = th >> 1;
            int n = nf * 16 + (lane & 15);
            int q = lane >> 4;
            u16 o8[8];
            #pragma unroll
            for (int e = 0; e < 8; ++e) {
                float v = (q < 3) ? c1w[((size_t)(n * 8 + e) * 3 + ky) * 3 + q] : 0.f;
                u16 hh = f2bf(v);
                o8[e] = (h == 0) ? hh : f2bf(v - bf2f(hh));
            }
            u16* d = bp1 + (size_t)i * 8;
            #pragma unroll
            for (int e = 0; e < 8; ++e) d[e] = o8[e];
        }
    } else if (blk < 46) {
        bpack_body(c2w, bp2, 64, 64, 9, 2, 4, (blk - 10) * 256 + tid);
    } else if (blk < 82) {
        bpack_body(c3w, bp3, 64, 64, 9, 2, 4, (blk - 46) * 256 + tid);
    } else if (blk < 262) {
        bpack_body(c4w, bp4, 64, 257, 9, 2, 20, (blk - 82) * 256 + tid);
    } else if (blk < 505) {
        bpack_body(s2w, bp5, 257, 257, 3, 9, 18, (blk - 262) * 256 + tid);
    } else {
        int row = blk - 505;
        int prow = row % 130;
        int b = row / 130;
        bool inr = (prow >= 1 && prow <= 128);
        for (int i = tid; i < 8 * 130; i += 256) {
            int c = i / 130, pcol = i % 130;
            float v = 0.f;
            if (inr && pcol >= 1 && pcol <= 128)
                v = X[(((size_t)b * 8 + c) * 128 + (prow - 1)) * 128 + (pcol - 1)];
            Xs[c][pcol] = v;
        }
        __syncthreads();
        for (int p = tid; p < 130; p += 256) {
            short8 h8, l8;
            #pragma unroll
            for (int c = 0; c < 8; ++c) {
                float f = Xs[c][p];
                u16 hh = f2bf(f);
                h8[c] = (short)hh;
                l8[c] = (short)f2bf(f - bf2f(hh));
            }
            size_t o = (((size_t)b * 130 + prow) * 130 + p) * 16;
            *(short8*)(xp + o) = h8;
            *(short8*)(xp + o + 8) = l8;
        }
    }
}

// ---------------------------------------------------------------------------
// Zero borders: generic + fused-init (c2 + c4) variants.
// ---------------------------------------------------------------------------
__device__ __forceinline__ void zpad_body(u32* buf, int Hp, int Wp, int wpp, int doCols, long idx)
{
    int perB = 2 * Wp + (doCols ? 2 * (Hp - 2) : 0);
    int w = (int)(idx % wpp);
    long t = idx / wpp;
    int p = (int)(t % perB);
    int b = (int)(t / perB);
    int row, col;
    if (p < Wp) { row = 0; col = p; }
    else if (p < 2 * Wp) { row = Hp - 1; col = p - Wp; }
    else { int pp = p - 2 * Wp; row = 1 + (pp >> 1); col = (pp & 1) ? (Wp - 1) : 0; }
    buf[(((size_t)b * Hp + row) * Wp + col) * (size_t)wpp + w] = 0;
}

__global__ __launch_bounds__(256) void zpad(
    u32* buf, int Bn, int Hp, int Wp, int wpp, int doCols)
{
    int perB = 2 * Wp + (doCols ? 2 * (Hp - 2) : 0);
    long total = (long)Bn * perB * wpp;
    for (long idx = blockIdx.x * 256L + threadIdx.x; idx < total; idx += (long)gridDim.x * 256)
        zpad_body(buf, Hp, Wp, wpp, doCols, idx);
}

__global__ __launch_bounds__(256) void zpad_init(u32* c2b, u32* c4b)
{
    const long T1 = 64L * 260 * 64;   // c2: perB = 2*66 + 2*64
    const long T2 = 64L * 68 * 64;    // c4: perB = 2*18 + 2*16
    for (long idx = blockIdx.x * 256L + threadIdx.x; idx < T1 + T2; idx += (long)gridDim.x * 256) {
        if (idx < T1) zpad_body(c2b, 66, 66, 64, 1, idx);
        else          zpad_body(c4b, 18, 18, 64, 1, idx - T1);
    }
}

// ---------------------------------------------------------------------------
// conv1 dedicated: C=8, K packs 4 pixels x 8 ch (kx in K).  3 chunks.
// Full 3-term split; term-major interleave; in-register 2x2 pooling.
// ---------------------------------------------------------------------------
__global__ __launch_bounds__(256) void conv_c1(
    const u16* __restrict__ A, const u16* __restrict__ Bp,
    const float* __restrict__ esc, const float* __restrict__ ebi,
    u16* __restrict__ O)
{
    constexpr int Wst = 130, Hp = 130;
    constexpr int SROWS = 5;                 // 2 rows + 2 halo + 1 wrap-guard
    constexpr int SPIX = SROWS * Wst;        // 650
    __shared__ __align__(16) char sm[SPIX * 48];

    int bid = blockIdx.x;
    int ytile = bid % 64;
    int b = bid / 64;
    int y0 = ytile * 2;
    int tid = threadIdx.x;
    int wv = tid >> 6;
    int l = tid & 63;
    int r = l & 15, q = l >> 4;

    #pragma unroll
    for (int it = 0; it < 3; ++it) {
        int pix = tid + it * 256;
        int prow = y0 + pix / Wst, pcol = pix % Wst;
        uint4 v0 = {0, 0, 0, 0}, v1 = {0, 0, 0, 0};
        if (pix < SPIX && prow < Hp) {
            const u16* src = A + (((size_t)b * Hp + prow) * Wst + pcol) * 16;
            v0 = *(const uint4*)src;
            v1 = *(const uint4*)(src + 8);
        }
        if (pix < SPIX) {
            *(uint4*)(sm + pix * 48) = v0;
            *(uint4*)(sm + pix * 48 + 16) = v1;
        }
    }
    __syncthreads();

    f32x4 acc[4][4] = {};

    #pragma unroll
    for (int ky = 0; ky < 3; ++ky) {
        short8 bh[4], bl[4];
        #pragma unroll
        for (int ni = 0; ni < 4; ++ni) {
            const u16* bt = Bp + ((size_t)(ky * 2) * 4 + ni) * 512 + l * 8;
            bh[ni] = *(const short8*)bt;
            bl[ni] = *(const short8*)(bt + 4 * 512);
        }
        short8 ah[4], al[4];
        #pragma unroll
        for (int mi = 0; mi < 4; ++mi) {
            int pf = wv * 2 + (mi >> 1);
            int y = mi & 1;
            int p = (y + ky) * Wst + pf * 16 + r + q;   // wrap lands on guard row, zero-weighted
            ah[mi] = *(const short8*)(sm + p * 48);
            al[mi] = *(const short8*)(sm + p * 48 + 16);
        }
        #pragma unroll
        for (int ni = 0; ni < 4; ++ni)
            #pragma unroll
            for (int mi = 0; mi < 4; ++mi)
                acc[mi][ni] = __builtin_amdgcn_mfma_f32_16x16x32_bf16(ah[mi], bh[ni], acc[mi][ni], 0, 0, 0);
        #pragma unroll
        for (int ni = 0; ni < 4; ++ni)
            #pragma unroll
            for (int mi = 0; mi < 4; ++mi)
                acc[mi][ni] = __builtin_amdgcn_mfma_f32_16x16x32_bf16(ah[mi], bl[ni], acc[mi][ni], 0, 0, 0);
        #pragma unroll
        for (int ni = 0; ni < 4; ++ni)
            #pragma unroll
            for (int mi = 0; mi < 4; ++mi)
                acc[mi][ni] = __builtin_amdgcn_mfma_f32_16x16x32_bf16(al[mi], bh[ni], acc[mi][ni], 0, 0, 0);
    }

    // in-register BN+ReLU+2x2 pool -> unified c2 (66x66, 2 sections)
    #pragma unroll
    for (int ni = 0; ni < 4; ++ni) {
        int oc = ni * 16 + r;
        float sc0 = esc[oc], bi0 = ebi[oc];
        #pragma unroll
        for (int pi = 0; pi < 2; ++pi) {
            int pf = wv * 2 + pi;
            #pragma unroll
            for (int k = 0; k < 2; ++k) {
                float m = -3.4e38f;
                #pragma unroll
                for (int dmi = 0; dmi < 2; ++dmi)
                    #pragma unroll
                    for (int dj = 0; dj < 2; ++dj)
                        m = fmaxf(m, fmaf(acc[2 * pi + dmi][ni][2 * k + dj], sc0, bi0));
                m = fmaxf(m, 0.f);
                int x2 = pf * 8 + q * 2 + k;
                size_t base = (((size_t)b * 66 + (y0 / 2 + 1)) * 66 + (x2 + 1)) * 128;
                u16* d = O + base + ((oc >> 5) << 6) + (oc & 31);
                u16 hh = f2bf(m);
                d[0] = hh;
                d[32] = f2bf(m - bf2f(hh));
            }
        }
    }
}

// ---------------------------------------------------------------------------
// Shift-GEMM conv (C=64) via MFMA bf16 3-term split.  Unified layout, CSECT=2,
// XOR-swizzled LDS, direct dual-load staging, B prefetch, term-major.
// OUTMODE 0: BN+ReLU+pool2 -> unified NHWC;  OUTMODE 1: -> f32 NHWC
// ---------------------------------------------------------------------------
template<int H, int W, int OC, int R, int NF, int MFW, int OUTMODE, int NFTOT>
__global__ __launch_bounds__(256) void conv_gemm(
    const u16* __restrict__ A, const u16* __restrict__ Bp,
    const float* __restrict__ esc, const float* __restrict__ ebi,
    u16* __restrict__ O, float* __restrict__ Of)
{
    constexpr int Wst = W + 2, Hp = H + 2;
    constexpr int SROWS = R + 2;
    constexpr int SPIX = SROWS * Wst;
    constexpr int XF = W / 16;
    constexpr int HT = H / R;
    constexpr int GR = SPIX * 4;              // 32-B granules per phase
    constexpr int ROUNDS = (GR + 255) / 256;
    __shared__ __align__(16) char sm[SPIX * 128];

    int bid = blockIdx.x;
    int ytile = bid % HT;
    int b = bid / HT;
    int tid = threadIdx.x;
    int wv = tid >> 6;
    int l = tid & 63;
    int r = l & 15, q = l >> 4;
    int y0 = ytile * R;
    int nfg0 = blockIdx.y * NF;

    f32x4 acc[MFW][NF] = {};
    short8 Bh[2][NF], Bl[2][NF];

    auto loadB = [&](int buf, int chunk) {
        #pragma unroll
        for (int ni = 0; ni < NF; ++ni) {
            const u16* bt = Bp + ((size_t)(chunk * 2) * NFTOT + nfg0 + ni) * 512 + l * 8;
            Bh[buf][ni] = *(const short8*)bt;
            Bl[buf][ni] = *(const short8*)(bt + (size_t)NFTOT * 512);
        }
    };

    auto stage = [&](int cs) {
        #pragma unroll
        for (int it = 0; it < ROUNDS; ++it) {
            int idx = tid + it * 256;
            int pix = idx >> 2, sub = idx & 3;
            int prow = y0 + pix / Wst, pcol = pix % Wst;
            uint4 v0 = {0, 0, 0, 0}, v1 = {0, 0, 0, 0};
            if (idx < GR && prow < Hp) {
                const u16* src = A + (((size_t)b * Hp + prow) * Wst + pcol) * 128 + cs * 64 + sub * 8;
                v0 = *(const uint4*)src;
                v1 = *(const uint4*)(src + 32);
            }
            if (idx < GR) {
                *(uint4*)(sm + pix * 128 + ((sub ^ (pix & 7)) << 4)) = v0;
                *(uint4*)(sm + pix * 128 + (((sub + 4) ^ (pix & 7)) << 4)) = v1;
            }
        }
    };

    auto computePhase = [&](auto csc) {
        constexpr int cs = decltype(csc)::value;
        #pragma unroll
        for (int s = 0; s < 9; ++s) {
            int cur = (cs * 9 + s) & 1;            // compile-time (unrolled)
            if (s < 8) loadB(cur ^ 1, (s + 1) * 2 + cs);
            else if (cs == 0) loadB(cur ^ 1, 1);   // s=0 of section 1
            int ky = s / 3, kx = s % 3;
            short8 ah[MFW], al[MFW];
            #pragma unroll
            for (int mi = 0; mi < MFW; ++mi) {
                int pf = wv * (MFW / 2) + (mi >> 1);
                int y = (pf / XF) * 2 + (mi & 1);
                int xf = pf % XF;
                int p = (y + ky) * Wst + xf * 16 + kx + r;
                int off = p * 128 + ((q ^ (p & 7)) << 4);
                ah[mi] = *(const short8*)(sm + off);
                al[mi] = *(const short8*)(sm + (off ^ 64));
            }
            // term-major: NF*MFW independent MFMAs between dependent uses
            #pragma unroll
            for (int ni = 0; ni < NF; ++ni)
                #pragma unroll
                for (int mi = 0; mi < MFW; ++mi)
                    acc[mi][ni] = __builtin_amdgcn_mfma_f32_16x16x32_bf16(ah[mi], Bh[cur][ni], acc[mi][ni], 0, 0, 0);
            #pragma unroll
            for (int ni = 0; ni < NF; ++ni)
                #pragma unroll
                for (int mi = 0; mi < MFW; ++mi)
                    acc[mi][ni] = __builtin_amdgcn_mfma_f32_16x16x32_bf16(ah[mi], Bl[cur][ni], acc[mi][ni], 0, 0, 0);
            #pragma unroll
            for (int ni = 0; ni < NF; ++ni)
                #pragma unroll
                for (int mi = 0; mi < MFW; ++mi)
                    acc[mi][ni] = __builtin_amdgcn_mfma_f32_16x16x32_bf16(al[mi], Bh[cur][ni], acc[mi][ni], 0, 0, 0);
        }
    };

    stage(0);
    loadB(0, 0);   // chunk = s*2+cs
    __syncthreads();
    computePhase(IC<0>{});
    __syncthreads();
    stage(1);
    __syncthreads();
    computePhase(IC<1>{});

    // in-register BN+ReLU+2x2 pool epilogue
    #pragma unroll
    for (int ni = 0; ni < NF; ++ni) {
        int oc = (nfg0 + ni) * 16 + r;
        float sc0 = esc[oc], bi0 = ebi[oc];   // bns regions 512-padded: safe oc<320
        #pragma unroll
        for (int pi = 0; pi < MFW / 2; ++pi) {
            int pf = wv * (MFW / 2) + pi;
            int y2 = y0 / 2 + pf / XF;
            int xb = (pf % XF) * 8 + q * 2;
            #pragma unroll
            for (int k = 0; k < 2; ++k) {
                float m = -3.4e38f;
                #pragma unroll
                for (int dmi = 0; dmi < 2; ++dmi)
                    #pragma unroll
                    for (int dj = 0; dj < 2; ++dj)
                        m = fmaxf(m, fmaf(acc[2 * pi + dmi][ni][2 * k + dj], sc0, bi0));
                m = fmaxf(m, 0.f);
                int x2 = xb + k;
                if (OUTMODE == 0) {
                    size_t base = (((size_t)b * (H / 2 + 2) + y2 + 1) * (W / 2 + 2) + (x2 + 1)) * 128;
                    u16* d = O + base + ((oc >> 5) << 6) + (oc & 31);
                    u16 hh = f2bf(m);
                    d[0] = hh;
                    d[32] = f2bf(m - bf2f(hh));
                } else {
                    if (oc < OC)
                        Of[(((size_t)b * (H / 2) + y2) * (W / 2) + x2) * (size_t)OC + oc] = m;
                }
            }
        }
    }
}

// ---------------------------------------------------------------------------
// convs2 GEMM, t-split x3 (128 t/block), direct staging, term-major (3-term),
// FUSED attention partial sums -> part[b][3][257].
// A: mu unified (b,362,9x128B).  Out sp2 (b,360,257) f32.
// ---------------------------------------------------------------------------
__global__ __launch_bounds__(256) void convs2_gemm(
    const u16* __restrict__ A, const u16* __restrict__ Bp,
    const float* __restrict__ bia, float* __restrict__ sp2,
    float* __restrict__ part)
{
    constexpr int SPIX = 130;
    constexpr int GR = SPIX * 4;     // 520
    __shared__ __align__(16) char sm[SPIX * 128];

    int bid = blockIdx.x;
    int tt = bid % 3;
    int b = bid / 3;
    int nt = blockIdx.y;
    int t0 = tt * 128;
    int tid = threadIdx.x;
    int wv = tid >> 6;
    int l = tid & 63;
    int r = l & 15, q = l >> 4;

    f32x4 acc[2][3] = {};
    short8 Bh[2][3], Bl[2][3];

    auto loadB = [&](int buf, int chunk) {
        #pragma unroll
        for (int ni = 0; ni < 3; ++ni) {
            const u16* bt = Bp + ((size_t)(chunk * 2) * 18 + nt * 3 + ni) * 512 + l * 8;
            Bh[buf][ni] = *(const short8*)bt;
            Bl[buf][ni] = *(const short8*)(bt + 18 * 512);
        }
    };

    auto stage = [&](int cs) {
        #pragma unroll
        for (int it = 0; it < 3; ++it) {
            int idx = tid + it * 256;
            int pix = idx >> 2, sub = idx & 3;
            int gp = t0 + pix;
            uint4 v0 = {0, 0, 0, 0}, v1 = {0, 0, 0, 0};
            if (idx < GR && gp < 362) {
                const u16* src = A + ((size_t)b * 362 + gp) * 576 + cs * 64 + sub * 8;
                v0 = *(const uint4*)src;
                v1 = *(const uint4*)(src + 32);
            }
            if (idx < GR) {
                *(uint4*)(sm + pix * 128 + ((sub ^ (pix & 7)) << 4)) = v0;
                *(uint4*)(sm + pix * 128 + (((sub + 4) ^ (pix & 7)) << 4)) = v1;
            }
        }
    };

    stage(0);
    loadB(0, 0);   // chunk = ky*9 + cs
    __syncthreads();

    #pragma unroll
    for (int cs = 0; cs < 9; ++cs) {
        #pragma unroll
        for (int ky = 0; ky < 3; ++ky) {
            int cur = (cs * 3 + ky) & 1;       // compile-time (unrolled)
            if (ky < 2) loadB(cur ^ 1, (ky + 1) * 9 + cs);
            else if (cs < 8) loadB(cur ^ 1, cs + 1);
            short8 ah[2], al[2];
            #pragma unroll
            for (int mi = 0; mi < 2; ++mi) {
                int p = (wv * 2 + mi) * 16 + r + ky;
                int off = p * 128 + ((q ^ (p & 7)) << 4);
                ah[mi] = *(const short8*)(sm + off);
                al[mi] = *(const short8*)(sm + (off ^ 64));
            }
            // term-major: 6 independent MFMAs between dependent uses
            #pragma unroll
            for (int ni = 0; ni < 3; ++ni)
                #pragma unroll
                for (int mi = 0; mi < 2; ++mi)
                    acc[mi][ni] = __builtin_amdgcn_mfma_f32_16x16x32_bf16(ah[mi], Bh[cur][ni], acc[mi][ni], 0, 0, 0);
            #pragma unroll
            for (int ni = 0; ni < 3; ++ni)
                #pragma unroll
                for (int mi = 0; mi < 2; ++mi)
                    acc[mi][ni] = __builtin_amdgcn_mfma_f32_16x16x32_bf16(ah[mi], Bl[cur][ni], acc[mi][ni], 0, 0, 0);
            #pragma unroll
            for (int ni = 0; ni < 3; ++ni)
                #pragma unroll
                for (int mi = 0; mi < 2; ++mi)
                    acc[mi][ni] = __builtin_amdgcn_mfma_f32_16x16x32_bf16(al[mi], Bh[cur][ni], acc[mi][ni], 0, 0, 0);
        }
        __syncthreads();
        if (cs < 8) {
            stage(cs + 1);
            __syncthreads();
        }
    }

    // epilogue: bias + leaky store, accumulating per-thread t-partials
    float psum[3] = {0.f, 0.f, 0.f};
    #pragma unroll
    for (int ni = 0; ni < 3; ++ni) {
        int n = (nt * 3 + ni) * 16 + r;
        if (n >= NFB) continue;
        float bi0 = bia[n];
        #pragma unroll
        for (int mi = 0; mi < 2; ++mi) {
            int tb = t0 + (wv * 2 + mi) * 16 + q * 4;
            #pragma unroll
            for (int j = 0; j < 4; ++j) {
                int t = tb + j;
                if (t < NANG) {
                    float v = acc[mi][ni][j] + bi0;
                    v = (v >= 0.f) ? v : 0.1f * v;
                    sp2[((size_t)b * NANG + t) * NFB + n] = v;
                    psum[ni] += v;
                }
            }
        }
    }
    // reduce psum over q (shfl) then over waves (LDS), write part[b][tt][f]
    float* wred = (float*)sm;                 // 4 waves x 3 ni x 16 r
    #pragma unroll
    for (int ni = 0; ni < 3; ++ni) {
        float s = psum[ni];
        s += __shfl_down(s, 32, 64);
        s += __shfl_down(s, 16, 64);
        if (q == 0) wred[(wv * 3 + ni) * 16 + r] = s;
    }
    __syncthreads();
    if (tid < 48) {
        int ni = tid / 16, rr = tid % 16;
        float tot = wred[(0 * 3 + ni) * 16 + rr] + wred[(1 * 3 + ni) * 16 + rr]
                  + wred[(2 * 3 + ni) * 16 + rr] + wred[(3 * 3 + ni) * 16 + rr];
        int n = (nt * 3 + ni) * 16 + rr;
        if (n < NFB) part[((size_t)b * 3 + tt) * NFB + n] = tot;
    }
}

// ---------------------------------------------------------------------------
// FC: z (b, 64 pix, 257 f) NHWC f32 -> zfc (b, f, 32)
// ---------------------------------------------------------------------------
__global__ __launch_bounds__(256) void fc_kernel(
    const float* __restrict__ z, const float* __restrict__ fw,
    const float* __restrict__ fb, float* __restrict__ zfc)
{
    int bid = blockIdx.x;
    int ftile = bid % 33;
    int b = bid / 33;
    int j = threadIdx.x & 31;
    int f = ftile * 8 + (threadIdx.x >> 5);
    if (f >= 257) return;
    const float* zb = z + (size_t)b * 16448;
    float a = fb[j];
    #pragma unroll 8
    for (int s = 0; s < 64; ++s) a = fmaf(zb[s * 257 + f], fw[j * 64 + s], a);
    zfc[((size_t)b * 257 + f) * 32 + j] = a;
}

// ---------------------------------------------------------------------------
// Per-thread 4x4 Hermitian eigh (complex Jacobi, f64) -> Re(Un Un^H)
// 256-thread blocks for wave packing (identical per-thread math).
// ---------------------------------------------------------------------------
__global__ __launch_bounds__(256) void eigh_kernel(const float* __restrict__ z, double* __restrict__ rp)
{
    int idx = blockIdx.x * 256 + threadIdx.x;
    if (idx >= NB * NFB) return;
    const float* zr = z + (size_t)idx * 32;
    double Ar[4][4], Ai[4][4], Vr[4][4], Vi[4][4];
    #pragma unroll
    for (int m = 0; m < 4; ++m)
        #pragma unroll
        for (int n = 0; n < 4; ++n) {
            Ar[m][n] = 0.5 * ((double)zr[m * 8 + n] + (double)zr[n * 8 + m]);
            Ai[m][n] = 0.5 * ((double)zr[m * 8 + n + 4] - (double)zr[n * 8 + m + 4]);
            Vr[m][n] = (m == n) ? 1.0 : 0.0;
            Vi[m][n] = 0.0;
        }
    #pragma unroll
    for (int m = 0; m < 4; ++m) Ar[m][m] += 1e-5;

    for (int sweep = 0; sweep < 8; ++sweep) {
        #pragma unroll
        for (int p = 0; p < 3; ++p)
            #pragma unroll
            for (int qq = p + 1; qq < 4; ++qq) {
                double apr = Ar[p][qq], api = Ai[p][qq];
                double rmod = sqrt(apr * apr + api * api);
                if (rmod < 1e-300) continue;
                double cph = apr / rmod, sph = api / rmod;
                double tau = (Ar[qq][qq] - Ar[p][p]) / (2.0 * rmod);
                double t = (tau >= 0.0) ? (-1.0 / (tau + sqrt(1.0 + tau * tau)))
                                        : (1.0 / (-tau + sqrt(1.0 + tau * tau)));
                double c = 1.0 / sqrt(1.0 + t * t);
                double s = t * c;
                double wr = s * cph, wi = s * sph;
                #pragma unroll
                for (int i = 0; i < 4; ++i) {
                    double xr = Ar[i][p], xi = Ai[i][p];
                    double yr = Ar[i][qq], yi = Ai[i][qq];
                    Ar[i][p] = c * xr + (wr * yr + wi * yi);
                    Ai[i][p] = c * xi + (wr * yi - wi * yr);
                    Ar[i][qq] = c * yr - (wr * xr - wi * xi);
                    Ai[i][qq] = c * yi - (wr * xi + wi * xr);
                }
                #pragma unroll
                for (int i = 0; i < 4; ++i) {
                    double xr = Ar[p][i], xi = Ai[p][i];
                    double yr = Ar[qq][i], yi = Ai[qq][i];
                    Ar[p][i] = c * xr + (wr * yr - wi * yi);
                    Ai[p][i] = c * xi + (wr * yi + wi * yr);
                    Ar[qq][i] = c * yr - (wr * xr + wi * xi);
                    Ai[qq][i] = c * yi - (wr * xi - wi * xr);
                }
                #pragma unroll
                for (int i = 0; i < 4; ++i) {
                    double xr = Vr[i][p], xi = Vi[i][p];
                    double yr = Vr[i][qq], yi = Vi[i][qq];
                    Vr[i][p] = c * xr + (wr * yr + wi * yi);
                    Vi[i][p] = c * xi + (wr * yi - wi * yr);
                    Vr[i][qq] = c * yr - (wr * xr - wi * xi);
                    Vi[i][qq] = c * yi - (wr * xi + wi * xr);
                }
            }
    }
    double ev[4] = {Ar[0][0], Ar[1][1], Ar[2][2], Ar[3][3]};
    int i0 = 0;
    #pragma unroll
    for (int k = 1; k < 4; ++k) if (ev[k] < ev[i0]) i0 = k;
    int i1 = (i0 == 0) ? 1 : 0;
    #pragma unroll
    for (int k = 0; k < 4; ++k) if (k != i0 && ev[k] < ev[i1]) i1 = k;
    double* o = rp + (size_t)idx * 16;
    #pragma unroll
    for (int m = 0; m < 4; ++m)
        #pragma unroll
        for (int n = 0; n < 4; ++n)
            o[m * 4 + n] = Vr[m][i0] * Vr[n][i0] + Vi[m][i0] * Vi[n][i0]
                         + Vr[m][i1] * Vr[n][i1] + Vi[m][i1] * Vi[n][i1];
}

// ---------------------------------------------------------------------------
// MUSIC spectrum -> unified mu (b, t=a+1 in 362, 9 sections of [hi32|lo32]).
// Symmetric 10-term quadratic form (P symmetric; off-diag pre-doubled) +
// all-loads-prefetched (8 in-flight per thread) for MLP.  [round-12 optimum]
// ---------------------------------------------------------------------------
__global__ __launch_bounds__(256) void music_kernel(
    const float4* __restrict__ svr, const float4* __restrict__ svi,
    const double* __restrict__ rp, u16* __restrict__ mu)
{
    __shared__ double P[32][10];
    __shared__ float T[32][33];
    int bid = blockIdx.x;
    int at = bid % 12; bid /= 12;
    int ft = bid % 9;
    int b = bid / 9;
    int f0 = ft * 32, a0 = at * 32;
    int tid = threadIdx.x;
    // stage P compressed: j -> (m,n) pairs; off-diag doubled
    for (int i = tid; i < 32 * 10; i += 256) {
        int fi = i / 10, j = i % 10;
        const int mm[10] = {0, 1, 2, 3, 0, 0, 0, 1, 1, 2};
        const int nn[10] = {0, 1, 2, 3, 1, 2, 3, 2, 3, 3};
        int f = f0 + fi;
        double v = 0.0;
        if (f < 257) {
            v = rp[((size_t)b * 257 + f) * 16 + mm[j] * 4 + nn[j]];
            if (j >= 4) v += v;
        }
        P[fi][j] = v;
    }
    __syncthreads();
    int asub = tid & 31, fsub = tid >> 5;
    int a = a0 + asub;
    bool av = (a < 360);
    // prefetch ALL loads (8 independent) before any f64 compute
    float4 u[4], w[4];
    #pragma unroll
    for (int k2 = 0; k2 < 4; ++k2) {
        int f = f0 + fsub + 8 * k2;
        u[k2] = (float4){0.f, 0.f, 0.f, 0.f};
        w[k2] = (float4){0.f, 0.f, 0.f, 0.f};
        if (av && f < 257) {
            u[k2] = svr[((size_t)b * 257 + f) * 360 + a];
            w[k2] = svi[((size_t)b * 257 + f) * 360 + a];
        }
    }
    #pragma unroll
    for (int k2 = 0; k2 < 4; ++k2) {
        int fl = fsub + 8 * k2;
        double ua[4] = {u[k2].x, u[k2].y, u[k2].z, u[k2].w};
        double wa[4] = {w[k2].x, w[k2].y, w[k2].z, w[k2].w};
        const double* Pf = P[fl];
        const int mm[10] = {0, 1, 2, 3, 0, 0, 0, 1, 1, 2};
        const int nn[10] = {0, 1, 2, 3, 1, 2, 3, 2, 3, 3};
        double den = 0.0;
        #pragma unroll
        for (int j = 0; j < 10; ++j)
            den += Pf[j] * (ua[mm[j]] * ua[nn[j]] - wa[mm[j]] * wa[nn[j]]);
        T[asub][fl] = (float)(1.0 / fmax(den, 1e-6));
    }
    __syncthreads();
    int sec0 = f0 >> 5;
    #pragma unroll
    for (int p = 0; p < 4; ++p) {
        int row = p * 8 + (tid >> 5);
        int fc = tid & 31;
        int a2 = a0 + row;
        if (a2 < 360) {
            float v = T[row][fc];
            u16* d = mu + ((size_t)b * 362 + a2 + 1) * 576 + (size_t)sec0 * 64 + fc;
            u16 hh = f2bf(v);
            d[0] = hh;
            d[32] = f2bf(v - bf2f(hh));
        }
    }
}

// ---------------------------------------------------------------------------
// attention finish (mean -> MLP -> sigmoid); part has 3 chunks per b.
// h-dot parallelized: 16 h x 16 threads.
// ---------------------------------------------------------------------------
__global__ __launch_bounds__(256) void attn_finish(
    const float* __restrict__ part, const float* __restrict__ w1,
    const float* __restrict__ w2, float* __restrict__ att)
{
    __shared__ float ys[257];
    __shared__ float hp[16][17];
    __shared__ float hs[16];
    int b = blockIdx.x;
    int tid = threadIdx.x;
    for (int f = tid; f < 257; f += 256) {
        float s = part[((size_t)b * 3 + 0) * 257 + f]
                + part[((size_t)b * 3 + 1) * 257 + f]
                + part[((size_t)b * 3 + 2) * 257 + f];
        ys[f] = s * (1.0f / 360.0f);
    }
    __syncthreads();
    {
        int h = tid >> 4, seg = tid & 15;
        float p = 0.f;
        for (int c = seg; c < 257; c += 16)
            p = fmaf(ys[c], w1[(size_t)h * 257 + c], p);
        hp[h][seg] = p;
    }
    __syncthreads();
    if (tid < 16) {
        float s = 0.f;
        #pragma unroll
        for (int k = 0; k < 16; ++k) s += hp[tid][k];
        hs[tid] = fmaxf(s, 0.f);
    }
    __syncthreads();
    for (int o = tid; o < 257; o += 256) {
        float a = 0.f;
        #pragma unroll
        for (int j = 0; j < 16; ++j) a = fmaf(hs[j], w2[(size_t)o * 16 + j], a);
        att[(size_t)b * 257 + o] = 1.0f / (1.0f + expf(-a));
    }
}

// ---------------------------------------------------------------------------
// conv1d 257->1 over att-weighted sp2(b,t,f), sigmoid -> outS (b,360)
// ---------------------------------------------------------------------------
__global__ __launch_bounds__(256) void convs1_kernel(
    const float* __restrict__ sp2, const float* __restrict__ att,
    const float* __restrict__ w, const float* __restrict__ bb,
    float* __restrict__ outS)
{
    int bid = blockIdx.x;
    int tt = bid % 90;
    int b = bid / 90;
    int wv = threadIdx.x >> 6, l = threadIdx.x & 63;
    int t = tt * 4 + wv;
    float s = 0.f;
    for (int f = l; f < 257; f += 64) {
        float av = att[(size_t)b * 257 + f];
        float w0 = w[f * 3] * av, w1 = w[f * 3 + 1] * av, w2 = w[f * 3 + 2] * av;
        const float* col = sp2 + (size_t)b * 360 * 257 + f;
        if (t > 0)   s = fmaf(w0, col[(size_t)(t - 1) * 257], s);
        s = fmaf(w1, col[(size_t)t * 257], s);
        if (t < 359) s = fmaf(w2, col[(size_t)(t + 1) * 257], s);
    }
    #pragma unroll
    for (int off = 32; off > 0; off >>= 1) s += __shfl_down(s, off, 64);
    if (l == 0) outS[(size_t)b * 360 + t] = 1.0f / (1.0f + expf(-(s + bb[0])));
}

// ---------------------------------------------------------------------------
// top-5 soft-argmax, wave-parallel (strict >, index asc tie-break)
// ---------------------------------------------------------------------------
__global__ __launch_bounds__(64) void doa_kernel(const float* __restrict__ spec, float* __restrict__ doa)
{
    int b = blockIdx.x;
    int l = threadIdx.x;
    const float* s = spec + (size_t)b * NANG;
    float v[6];
    #pragma unroll
    for (int j = 0; j < 6; ++j) {
        int idx = l + 64 * j;
        v[j] = (idx < NANG) ? s[idx] : -3.4e38f;
    }
    float wvv[5]; int wii[5];
    #pragma unroll
    for (int k = 0; k < 5; ++k) {
        float bv = v[0]; int bj = 0;
        #pragma unroll
        for (int j = 1; j < 6; ++j)
            if (v[j] > bv) { bv = v[j]; bj = j; }
        int bi = l + 64 * bj;
        #pragma unroll
        for (int off = 1; off < 64; off <<= 1) {
            float ov = __shfl_xor(bv, off, 64);
            int oi = __shfl_xor(bi, off, 64);
            if (ov > bv || (ov == bv && oi < bi)) { bv = ov; bi = oi; }
        }
        wvv[k] = bv; wii[k] = bi;
        if ((bi & 63) == l) {
            int j = bi >> 6;
            #pragma unroll
            for (int jj = 0; jj < 6; ++jj)
                if (jj == j) v[jj] = -3.4e38f;
        }
    }
    if (l == 0) {
        float m = wvv[0];
        float wsum = 0.f, asum = 0.f;
        #pragma unroll
        for (int k = 0; k < 5; ++k) {
            float e = expf(20.0f * (wvv[k] - m));
            wsum += e;
            asum += e * (float)wii[k];
        }
        doa[b] = asum / wsum;
    }
}

// ---------------------------------------------------------------------------
extern "C" void kernel_launch(void* const* d_in, const int* in_sizes, int n_in,
                              void* d_out, int out_size, void* d_ws, size_t ws_size,
                              hipStream_t stream)
{
    const float* X    = (const float*)d_in[0];
    const float* svr  = (const float*)d_in[1];
    const float* svi  = (const float*)d_in[2];
    const float* c1w  = (const float*)d_in[4];
    const float* c2w  = (const float*)d_in[5];
    const float* c3w  = (const float*)d_in[6];
    const float* c4w  = (const float*)d_in[7];
    const float* fcw  = (const float*)d_in[8];
    const float* fcb  = (const float*)d_in[9];
    const float* s2w  = (const float*)d_in[10];
    const float* s2b  = (const float*)d_in[11];
    const float* s1w  = (const float*)d_in[12];
    const float* s1b  = (const float*)d_in[13];
    const float* caw1 = (const float*)d_in[14];
    const float* caw2 = (const float*)d_in[15];
    const float* bn1g = (const float*)d_in[16]; const float* bn1b = (const float*)d_in[17];
    const float* bn1m = (const float*)d_in[18]; const float* bn1v = (const float*)d_in[19];
    const float* bn2g = (const float*)d_in[20]; const float* bn2b = (const float*)d_in[21];
    const float* bn2m = (const float*)d_in[22]; const float* bn2v = (const float*)d_in[23];
    const float* bn3g = (const float*)d_in[24]; const float* bn3b = (const float*)d_in[25];
    const float* bn3m = (const float*)d_in[26]; const float* bn3v = (const float*)d_in[27];
    const float* bn4g = (const float*)d_in[28]; const float* bn4b = (const float*)d_in[29];
    const float* bn4m = (const float*)d_in[30]; const float* bn4v = (const float*)d_in[31];

    char* wsb = (char*)d_ws;
    // region A (time-disjoint: xp -> c3 -> mu)
    u16* xp = (u16*)(wsb + 0);               // 34,611,200 B (64x130x130x32B)
    u16* c3 = (u16*)(wsb + 0);               // 18,939,904 B (64x34x34x256B)
    u16* mu = (u16*)(wsb + 0);               // 26,689,536 B (64x362x1152B)
    // region B (c2 -> {zbuf, zfc, rp, sp2, part, att})
    const size_t Bb = 34611200;
    u16*   c2  = (u16*)(wsb + Bb);           // 71,368,704 B (64x66x66x256B)
    float*  zbuf = (float*)(wsb + Bb);
    float*  zfc  = (float*)(wsb + Bb + 4210688);
    double* rp   = (double*)(wsb + Bb + 6316032);
    float*  sp2  = (float*)(wsb + Bb + 8421376);
    float*  part = (float*)(wsb + Bb + 32106496);
    float*  att  = (float*)(wsb + Bb + 32501248);
    // region C (persistent small)
    const size_t Cb = Bb + 71368704;
    u16* c4  = (u16*)(wsb + Cb);             // 5,308,416 B (64x18x18x256B)
    u16* bp1 = (u16*)(wsb + Cb + 5308416);
    u16* bp2 = (u16*)(wsb + Cb + 5382144);
    u16* bp3 = (u16*)(wsb + Cb + 5529600);
    u16* bp4 = (u16*)(wsb + Cb + 5677056);
    u16* bp5 = (u16*)(wsb + Cb + 6414336);
    float* bns = (float*)(wsb + Cb + 7409664);

    float* outD = (float*)d_out;
    float* outS = (float*)d_out + 64;

    // --- fused prep (bnprep + all bpacks + xpack) + fused init zpads ---
    prep_kernel<<<8825, 256, 0, stream>>>(
        X, xp, c1w, bp1, c2w, bp2, c3w, bp3, c4w, bp4, s2w, bp5,
        bn1g, bn1b, bn1m, bn1v, bn2g, bn2b, bn2m, bn2v,
        bn3g, bn3b, bn3m, bn3v, bn4g, bn4b, bn4m, bn4v, bns);
    zpad_init<<<2048, 256, 0, stream>>>((u32*)c2, (u32*)c4);

    // --- conv1 (3-term) ---
    conv_c1<<<64 * 64, 256, 0, stream>>>(xp, bp1, bns, bns + 512, c2);
    zpad<<<2112, 256, 0, stream>>>((u32*)c3, 64, 34, 34, 64, 1);   // A region free now
    // --- conv2 (3-term) ---
    conv_gemm<64, 64, 64, 2, 4, 2, 0, 4>
        <<<dim3(64 * 32, 1), 256, 0, stream>>>(c2, bp2, bns + 1024, bns + 1536, c3, nullptr);
    // --- conv3 (3-term) ---
    conv_gemm<32, 32, 64, 4, 4, 2, 0, 4>
        <<<dim3(64 * 8, 1), 256, 0, stream>>>(c3, bp3, bns + 2048, bns + 2560, c4, nullptr);
    zpad<<<144, 256, 0, stream>>>((u32*)mu, 64, 362, 1, 288, 0);   // A region free now
    // --- conv4 (3-term) -> z f32 (b,8,8,257) ---
    conv_gemm<16, 16, 257, 8, 4, 2, 1, 20>
        <<<dim3(64 * 2, 5), 256, 0, stream>>>(c4, bp4, bns + 3072, bns + 3584, nullptr, zbuf);

    fc_kernel<<<64 * 33, 256, 0, stream>>>(zbuf, fcw, fcb, zfc);
    eigh_kernel<<<65, 256, 0, stream>>>(zfc, rp);
    music_kernel<<<64 * 108, 256, 0, stream>>>((const float4*)svr, (const float4*)svi, rp, mu);
    // --- convs2 (3-term, +fused attention partial sums) -> sp2, part ---
    convs2_gemm<<<dim3(64 * 3, 6), 256, 0, stream>>>(mu, bp5, s2b, sp2, part);

    attn_finish<<<64, 256, 0, stream>>>(part, caw1, caw2, att);
    convs1_kernel<<<64 * 90, 256, 0, stream>>>(sp2, att, s1w, s1b, outS);
    doa_kernel<<<64, 64, 0, stream>>>(outS, outD);
}

// Round 15
// 373.440 us; speedup vs baseline: 1.0612x; 1.0168x over previous
//
#include <hip/hip_runtime.h>

typedef unsigned short u16;
typedef unsigned int u32;
typedef short short8 __attribute__((ext_vector_type(8)));
typedef float f32x4 __attribute__((ext_vector_type(4)));

#define NB 64
#define NFB 257
#define NANG 360

template<int V> struct IC { static constexpr int value = V; };

__device__ __forceinline__ u16 f2bf(float x) {
    u32 u = __float_as_uint(x);
    u = (u + 0x7fffu + ((u >> 16) & 1u)) >> 16;
    return (u16)u;
}
__device__ __forceinline__ float bf2f(u16 h) { return __uint_as_float(((u32)h) << 16); }

// async global->LDS, 16B per lane; LDS dest = wave-uniform base + lane*16
__device__ __forceinline__ void glds16(const void* g, void* l3) {
    __builtin_amdgcn_global_load_lds(
        (const __attribute__((address_space(1))) void*)g,
        (__attribute__((address_space(3))) void*)l3, 16, 0, 0);
}

// ---------------------------------------------------------------------------
// Unified activation layout: per pixel, (C/32) sections of 128 B:
//   [hi ch0-31 (64B) | lo ch0-31 (64B)] [hi ch32-63 | lo ch32-63] ...
// NUMERICS NOTE (round-10 failure): all convs must keep the full 3-term
// bf16 split (Ah*Bh + Ah*Bl + Al*Bh ~ f32 quality).  2-term (B rounded to
// bf16) produced 0.2%/layer error that flipped near-degenerate eigenvector
// subspaces in eigh -> 1/denom chaos -> doa absmax 171.  Do not retry.
// PERF NOTE (rounds 12/13): music is occupancy/latency-bound.  8-load
// prefetch @ VGPR 40 / 56% occ is the local optimum; 16-load prefetch
// (VGPR 76, 28% occ) REGRESSED 69.5 -> 83 us.  Do not deepen prefetch.
// STAGING (round 15): conv_gemm/convs2 stage via global_load_lds width=16
// with pre-swizzled SOURCE (srcg = slot ^ (pix&7)) and LINEAR LDS dest --
// same bytes land in same slots as the old reg-round-trip XOR write.
// ---------------------------------------------------------------------------

// ---------------------------------------------------------------------------
// Fused prep: bnprep(4) | bpack1(6) | bpack c2(36) c3(36) c4(180) s2(243) |
// xpack(8320).  One launch, branch by block range.
// ---------------------------------------------------------------------------
__device__ __forceinline__ void bpack_body(
    const float* __restrict__ w, u16* __restrict__ Bp,
    int CREAL, int OCREAL, int NT, int KCC, int NFTOT, int i)
{
    int total = NT * KCC * 2 * NFTOT * 64;
    if (i >= total) return;
    int lane = i & 63;
    int t = i >> 6;
    int nf = t % NFTOT;
    int th = t / NFTOT;
    int h = th & 1;
    int chunk = th >> 1;
    int s = chunk / KCC, kc = chunk % KCC;
    int n = nf * 16 + (lane & 15);
    int k0 = kc * 32 + (lane >> 4) * 8;
    u16 o8[8];
    #pragma unroll
    for (int e = 0; e < 8; ++e) {
        int k = k0 + e;
        float v = 0.f;
        if (k < CREAL && n < OCREAL) v = w[((size_t)n * CREAL + k) * NT + s];
        u16 hh = f2bf(v);
        o8[e] = (h == 0) ? hh : f2bf(v - bf2f(hh));
    }
    u16* d = Bp + (size_t)i * 8;
    #pragma unroll
    for (int e = 0; e < 8; ++e) d[e] = o8[e];
}

__global__ __launch_bounds__(256) void prep_kernel(
    const float* __restrict__ X, u16* __restrict__ xp,
    const float* __restrict__ c1w, u16* __restrict__ bp1,
    const float* __restrict__ c2w, u16* __restrict__ bp2,
    const float* __restrict__ c3w, u16* __restrict__ bp3,
    const float* __restrict__ c4w, u16* __restrict__ bp4,
    const float* __restrict__ s2w, u16* __restrict__ bp5,
    const float* g1, const float* b1, const float* m1, const float* v1,
    const float* g2, const float* b2, const float* m2, const float* v2,
    const float* g3, const float* b3, const float* m3, const float* v3,
    const float* g4, const float* b4, const float* m4, const float* v4,
    float* __restrict__ bns)
{
    __shared__ float Xs[8][132];
    int blk = blockIdx.x;
    int tid = threadIdx.x;
    if (blk < 4) {
        int L = blk;
        const float* gs[4] = {g1, g2, g3, g4};
        const float* bs[4] = {b1, b2, b3, b4};
        const float* ms[4] = {m1, m2, m3, m4};
        const float* vs[4] = {v1, v2, v3, v4};
        int n = (L == 3) ? 257 : 64;
        float* sc = bns + L * 1024;
        float* bi = sc + 512;
        for (int i = tid; i < n; i += 256) {
            float s = gs[L][i] * rsqrtf(vs[L][i] + 1e-5f);
            sc[i] = s;
            bi[i] = bs[L][i] - ms[L][i] * s;
        }
    } else if (blk < 10) {
        int i = (blk - 4) * 256 + tid;
        if (i < 3 * 2 * 4 * 64) {
            int lane = i & 63;
            int t = i >> 6;
            int nf = t % 4;
            int th = t / 4;
            int h = th & 1;
            int ky = th >> 1;
            int n = nf * 16 + (lane & 15);
            int q = lane >> 4;
            u16 o8[8];
            #pragma unroll
            for (int e = 0; e < 8; ++e) {
                float v = (q < 3) ? c1w[((size_t)(n * 8 + e) * 3 + ky) * 3 + q] : 0.f;
                u16 hh = f2bf(v);
                o8[e] = (h == 0) ? hh : f2bf(v - bf2f(hh));
            }
            u16* d = bp1 + (size_t)i * 8;
            #pragma unroll
            for (int e = 0; e < 8; ++e) d[e] = o8[e];
        }
    } else if (blk < 46) {
        bpack_body(c2w, bp2, 64, 64, 9, 2, 4, (blk - 10) * 256 + tid);
    } else if (blk < 82) {
        bpack_body(c3w, bp3, 64, 64, 9, 2, 4, (blk - 46) * 256 + tid);
    } else if (blk < 262) {
        bpack_body(c4w, bp4, 64, 257, 9, 2, 20, (blk - 82) * 256 + tid);
    } else if (blk < 505) {
        bpack_body(s2w, bp5, 257, 257, 3, 9, 18, (blk - 262) * 256 + tid);
    } else {
        int row = blk - 505;
        int prow = row % 130;
        int b = row / 130;
        bool inr = (prow >= 1 && prow <= 128);
        for (int i = tid; i < 8 * 130; i += 256) {
            int c = i / 130, pcol = i % 130;
            float v = 0.f;
            if (inr && pcol >= 1 && pcol <= 128)
                v = X[(((size_t)b * 8 + c) * 128 + (prow - 1)) * 128 + (pcol - 1)];
            Xs[c][pcol] = v;
        }
        __syncthreads();
        for (int p = tid; p < 130; p += 256) {
            short8 h8, l8;
            #pragma unroll
            for (int c = 0; c < 8; ++c) {
                float f = Xs[c][p];
                u16 hh = f2bf(f);
                h8[c] = (short)hh;
                l8[c] = (short)f2bf(f - bf2f(hh));
            }
            size_t o = (((size_t)b * 130 + prow) * 130 + p) * 16;
            *(short8*)(xp + o) = h8;
            *(short8*)(xp + o + 8) = l8;
        }
    }
}

// ---------------------------------------------------------------------------
// Zero borders: generic + fused-init (c2 + c4) variants.
// ---------------------------------------------------------------------------
__device__ __forceinline__ void zpad_body(u32* buf, int Hp, int Wp, int wpp, int doCols, long idx)
{
    int perB = 2 * Wp + (doCols ? 2 * (Hp - 2) : 0);
    int w = (int)(idx % wpp);
    long t = idx / wpp;
    int p = (int)(t % perB);
    int b = (int)(t / perB);
    int row, col;
    if (p < Wp) { row = 0; col = p; }
    else if (p < 2 * Wp) { row = Hp - 1; col = p - Wp; }
    else { int pp = p - 2 * Wp; row = 1 + (pp >> 1); col = (pp & 1) ? (Wp - 1) : 0; }
    buf[(((size_t)b * Hp + row) * Wp + col) * (size_t)wpp + w] = 0;
}

__global__ __launch_bounds__(256) void zpad(
    u32* buf, int Bn, int Hp, int Wp, int wpp, int doCols)
{
    int perB = 2 * Wp + (doCols ? 2 * (Hp - 2) : 0);
    long total = (long)Bn * perB * wpp;
    for (long idx = blockIdx.x * 256L + threadIdx.x; idx < total; idx += (long)gridDim.x * 256)
        zpad_body(buf, Hp, Wp, wpp, doCols, idx);
}

__global__ __launch_bounds__(256) void zpad_init(u32* c2b, u32* c4b)
{
    const long T1 = 64L * 260 * 64;   // c2: perB = 2*66 + 2*64
    const long T2 = 64L * 68 * 64;    // c4: perB = 2*18 + 2*16
    for (long idx = blockIdx.x * 256L + threadIdx.x; idx < T1 + T2; idx += (long)gridDim.x * 256) {
        if (idx < T1) zpad_body(c2b, 66, 66, 64, 1, idx);
        else          zpad_body(c4b, 18, 18, 64, 1, idx - T1);
    }
}

// ---------------------------------------------------------------------------
// conv1 dedicated: C=8, K packs 4 pixels x 8 ch (kx in K).  3 chunks.
// Full 3-term split; term-major interleave; in-register 2x2 pooling.
// ---------------------------------------------------------------------------
__global__ __launch_bounds__(256) void conv_c1(
    const u16* __restrict__ A, const u16* __restrict__ Bp,
    const float* __restrict__ esc, const float* __restrict__ ebi,
    u16* __restrict__ O)
{
    constexpr int Wst = 130, Hp = 130;
    constexpr int SROWS = 5;                 // 2 rows + 2 halo + 1 wrap-guard
    constexpr int SPIX = SROWS * Wst;        // 650
    __shared__ __align__(16) char sm[SPIX * 48];

    int bid = blockIdx.x;
    int ytile = bid % 64;
    int b = bid / 64;
    int y0 = ytile * 2;
    int tid = threadIdx.x;
    int wv = tid >> 6;
    int l = tid & 63;
    int r = l & 15, q = l >> 4;

    #pragma unroll
    for (int it = 0; it < 3; ++it) {
        int pix = tid + it * 256;
        int prow = y0 + pix / Wst, pcol = pix % Wst;
        uint4 v0 = {0, 0, 0, 0}, v1 = {0, 0, 0, 0};
        if (pix < SPIX && prow < Hp) {
            const u16* src = A + (((size_t)b * Hp + prow) * Wst + pcol) * 16;
            v0 = *(const uint4*)src;
            v1 = *(const uint4*)(src + 8);
        }
        if (pix < SPIX) {
            *(uint4*)(sm + pix * 48) = v0;
            *(uint4*)(sm + pix * 48 + 16) = v1;
        }
    }
    __syncthreads();

    f32x4 acc[4][4] = {};

    #pragma unroll
    for (int ky = 0; ky < 3; ++ky) {
        short8 bh[4], bl[4];
        #pragma unroll
        for (int ni = 0; ni < 4; ++ni) {
            const u16* bt = Bp + ((size_t)(ky * 2) * 4 + ni) * 512 + l * 8;
            bh[ni] = *(const short8*)bt;
            bl[ni] = *(const short8*)(bt + 4 * 512);
        }
        short8 ah[4], al[4];
        #pragma unroll
        for (int mi = 0; mi < 4; ++mi) {
            int pf = wv * 2 + (mi >> 1);
            int y = mi & 1;
            int p = (y + ky) * Wst + pf * 16 + r + q;   // wrap lands on guard row, zero-weighted
            ah[mi] = *(const short8*)(sm + p * 48);
            al[mi] = *(const short8*)(sm + p * 48 + 16);
        }
        #pragma unroll
        for (int ni = 0; ni < 4; ++ni)
            #pragma unroll
            for (int mi = 0; mi < 4; ++mi)
                acc[mi][ni] = __builtin_amdgcn_mfma_f32_16x16x32_bf16(ah[mi], bh[ni], acc[mi][ni], 0, 0, 0);
        #pragma unroll
        for (int ni = 0; ni < 4; ++ni)
            #pragma unroll
            for (int mi = 0; mi < 4; ++mi)
                acc[mi][ni] = __builtin_amdgcn_mfma_f32_16x16x32_bf16(ah[mi], bl[ni], acc[mi][ni], 0, 0, 0);
        #pragma unroll
        for (int ni = 0; ni < 4; ++ni)
            #pragma unroll
            for (int mi = 0; mi < 4; ++mi)
                acc[mi][ni] = __builtin_amdgcn_mfma_f32_16x16x32_bf16(al[mi], bh[ni], acc[mi][ni], 0, 0, 0);
    }

    // in-register BN+ReLU+2x2 pool -> unified c2 (66x66, 2 sections)
    #pragma unroll
    for (int ni = 0; ni < 4; ++ni) {
        int oc = ni * 16 + r;
        float sc0 = esc[oc], bi0 = ebi[oc];
        #pragma unroll
        for (int pi = 0; pi < 2; ++pi) {
            int pf = wv * 2 + pi;
            #pragma unroll
            for (int k = 0; k < 2; ++k) {
                float m = -3.4e38f;
                #pragma unroll
                for (int dmi = 0; dmi < 2; ++dmi)
                    #pragma unroll
                    for (int dj = 0; dj < 2; ++dj)
                        m = fmaxf(m, fmaf(acc[2 * pi + dmi][ni][2 * k + dj], sc0, bi0));
                m = fmaxf(m, 0.f);
                int x2 = pf * 8 + q * 2 + k;
                size_t base = (((size_t)b * 66 + (y0 / 2 + 1)) * 66 + (x2 + 1)) * 128;
                u16* d = O + base + ((oc >> 5) << 6) + (oc & 31);
                u16 hh = f2bf(m);
                d[0] = hh;
                d[32] = f2bf(m - bf2f(hh));
            }
        }
    }
}

// ---------------------------------------------------------------------------
// Shift-GEMM conv (C=64) via MFMA bf16 3-term split.  Unified layout, CSECT=2,
// XOR-swizzled LDS (via pre-swizzled global_load_lds source), B prefetch,
// term-major interleave, in-register pooling.
// OUTMODE 0: BN+ReLU+pool2 -> unified NHWC;  OUTMODE 1: -> f32 NHWC
// ---------------------------------------------------------------------------
template<int H, int W, int OC, int R, int NF, int MFW, int OUTMODE, int NFTOT>
__global__ __launch_bounds__(256) void conv_gemm(
    const u16* __restrict__ A, const u16* __restrict__ Bp,
    const float* __restrict__ esc, const float* __restrict__ ebi,
    u16* __restrict__ O, float* __restrict__ Of)
{
    constexpr int Wst = W + 2, Hp = H + 2;
    constexpr int SROWS = R + 2;
    constexpr int SPIX = SROWS * Wst;
    constexpr int XF = W / 16;
    constexpr int HT = H / R;
    __shared__ __align__(16) char sm[SPIX * 128];

    int bid = blockIdx.x;
    int ytile = bid % HT;
    int b = bid / HT;
    int tid = threadIdx.x;
    int wv = tid >> 6;
    int l = tid & 63;
    int r = l & 15, q = l >> 4;
    int y0 = ytile * R;
    int nfg0 = blockIdx.y * NF;

    f32x4 acc[MFW][NF] = {};
    short8 Bh[2][NF], Bl[2][NF];

    auto loadB = [&](int buf, int chunk) {
        #pragma unroll
        for (int ni = 0; ni < NF; ++ni) {
            const u16* bt = Bp + ((size_t)(chunk * 2) * NFTOT + nfg0 + ni) * 512 + l * 8;
            Bh[buf][ni] = *(const short8*)bt;
            Bl[buf][ni] = *(const short8*)(bt + (size_t)NFTOT * 512);
        }
    };

    // async stage: LDS linear (it*1024 + lane*16); source pre-swizzled so
    // LDS slot s of pixel p holds global granule s^(p&7) -- identical layout
    // to the old XOR ds_write.  All pixels in-bounds (prow <= Hp-1 always).
    auto stage = [&](int cs) {
        constexpr int GRAN = SPIX * 8;           // 16B granules per phase
        constexpr int WIT = (GRAN + 63) / 64;
        for (int it2 = wv; it2 < WIT; it2 += 4) {
            int g = it2 * 64 + l;
            int pix = g >> 3, slot = g & 7;
            int srcg = slot ^ (pix & 7);
            int prow = y0 + pix / Wst, pcol = pix % Wst;
            const u16* src = A + (((size_t)b * Hp + prow) * Wst + pcol) * 128 + cs * 64 + srcg * 8;
            char* dst = sm + it2 * 1024 + l * 16;
            if (g < GRAN) glds16(src, dst);
        }
    };

    auto computePhase = [&](auto csc) {
        constexpr int cs = decltype(csc)::value;
        #pragma unroll
        for (int s = 0; s < 9; ++s) {
            int cur = (cs * 9 + s) & 1;            // compile-time (unrolled)
            if (s < 8) loadB(cur ^ 1, (s + 1) * 2 + cs);
            else if (cs == 0) loadB(cur ^ 1, 1);   // s=0 of section 1
            int ky = s / 3, kx = s % 3;
            short8 ah[MFW], al[MFW];
            #pragma unroll
            for (int mi = 0; mi < MFW; ++mi) {
                int pf = wv * (MFW / 2) + (mi >> 1);
                int y = (pf / XF) * 2 + (mi & 1);
                int xf = pf % XF;
                int p = (y + ky) * Wst + xf * 16 + kx + r;
                int off = p * 128 + ((q ^ (p & 7)) << 4);
                ah[mi] = *(const short8*)(sm + off);
                al[mi] = *(const short8*)(sm + (off ^ 64));
            }
            // term-major: NF*MFW independent MFMAs between dependent uses
            #pragma unroll
            for (int ni = 0; ni < NF; ++ni)
                #pragma unroll
                for (int mi = 0; mi < MFW; ++mi)
                    acc[mi][ni] = __builtin_amdgcn_mfma_f32_16x16x32_bf16(ah[mi], Bh[cur][ni], acc[mi][ni], 0, 0, 0);
            #pragma unroll
            for (int ni = 0; ni < NF; ++ni)
                #pragma unroll
                for (int mi = 0; mi < MFW; ++mi)
                    acc[mi][ni] = __builtin_amdgcn_mfma_f32_16x16x32_bf16(ah[mi], Bl[cur][ni], acc[mi][ni], 0, 0, 0);
            #pragma unroll
            for (int ni = 0; ni < NF; ++ni)
                #pragma unroll
                for (int mi = 0; mi < MFW; ++mi)
                    acc[mi][ni] = __builtin_amdgcn_mfma_f32_16x16x32_bf16(al[mi], Bh[cur][ni], acc[mi][ni], 0, 0, 0);
        }
    };

    stage(0);
    loadB(0, 0);   // chunk = s*2+cs
    __syncthreads();
    computePhase(IC<0>{});
    __syncthreads();
    stage(1);
    __syncthreads();
    computePhase(IC<1>{});

    // in-register BN+ReLU+2x2 pool epilogue
    #pragma unroll
    for (int ni = 0; ni < NF; ++ni) {
        int oc = (nfg0 + ni) * 16 + r;
        float sc0 = esc[oc], bi0 = ebi[oc];   // bns regions 512-padded: safe oc<320
        #pragma unroll
        for (int pi = 0; pi < MFW / 2; ++pi) {
            int pf = wv * (MFW / 2) + pi;
            int y2 = y0 / 2 + pf / XF;
            int xb = (pf % XF) * 8 + q * 2;
            #pragma unroll
            for (int k = 0; k < 2; ++k) {
                float m = -3.4e38f;
                #pragma unroll
                for (int dmi = 0; dmi < 2; ++dmi)
                    #pragma unroll
                    for (int dj = 0; dj < 2; ++dj)
                        m = fmaxf(m, fmaf(acc[2 * pi + dmi][ni][2 * k + dj], sc0, bi0));
                m = fmaxf(m, 0.f);
                int x2 = xb + k;
                if (OUTMODE == 0) {
                    size_t base = (((size_t)b * (H / 2 + 2) + y2 + 1) * (W / 2 + 2) + (x2 + 1)) * 128;
                    u16* d = O + base + ((oc >> 5) << 6) + (oc & 31);
                    u16 hh = f2bf(m);
                    d[0] = hh;
                    d[32] = f2bf(m - bf2f(hh));
                } else {
                    if (oc < OC)
                        Of[(((size_t)b * (H / 2) + y2) * (W / 2) + x2) * (size_t)OC + oc] = m;
                }
            }
        }
    }
}

// ---------------------------------------------------------------------------
// convs2 GEMM, t-split x3 (128 t/block), global_load_lds staging (source
// pre-swizzled, OOB rows clamped to zeroed pad row 361), term-major (3-term),
// FUSED attention partial sums -> part[b][3][257].
// A: mu unified (b,362,9x128B).  Out sp2 (b,360,257) f32.
// ---------------------------------------------------------------------------
__global__ __launch_bounds__(256) void convs2_gemm(
    const u16* __restrict__ A, const u16* __restrict__ Bp,
    const float* __restrict__ bia, float* __restrict__ sp2,
    float* __restrict__ part)
{
    constexpr int SPIX = 130;
    __shared__ __align__(16) char sm[SPIX * 128];

    int bid = blockIdx.x;
    int tt = bid % 3;
    int b = bid / 3;
    int nt = blockIdx.y;
    int t0 = tt * 128;
    int tid = threadIdx.x;
    int wv = tid >> 6;
    int l = tid & 63;
    int r = l & 15, q = l >> 4;

    f32x4 acc[2][3] = {};
    short8 Bh[2][3], Bl[2][3];

    auto loadB = [&](int buf, int chunk) {
        #pragma unroll
        for (int ni = 0; ni < 3; ++ni) {
            const u16* bt = Bp + ((size_t)(chunk * 2) * 18 + nt * 3 + ni) * 512 + l * 8;
            Bh[buf][ni] = *(const short8*)bt;
            Bl[buf][ni] = *(const short8*)(bt + 18 * 512);
        }
    };

    auto stage = [&](int cs) {
        constexpr int GRAN = SPIX * 8;           // 1040
        constexpr int WIT = (GRAN + 63) / 64;    // 17
        for (int it2 = wv; it2 < WIT; it2 += 4) {
            int g = it2 * 64 + l;
            int pix = g >> 3, slot = g & 7;
            int srcg = slot ^ (pix & 7);
            int gp = t0 + pix;
            if (gp > 361) gp = 361;              // pad row 361 is zeroed
            const u16* src = A + ((size_t)b * 362 + gp) * 576 + cs * 64 + srcg * 8;
            char* dst = sm + it2 * 1024 + l * 16;
            if (g < GRAN) glds16(src, dst);
        }
    };

    stage(0);
    loadB(0, 0);   // chunk = ky*9 + cs
    __syncthreads();

    #pragma unroll
    for (int cs = 0; cs < 9; ++cs) {
        #pragma unroll
        for (int ky = 0; ky < 3; ++ky) {
            int cur = (cs * 3 + ky) & 1;       // compile-time (unrolled)
            if (ky < 2) loadB(cur ^ 1, (ky + 1) * 9 + cs);
            else if (cs < 8) loadB(cur ^ 1, cs + 1);
            short8 ah[2], al[2];
            #pragma unroll
            for (int mi = 0; mi < 2; ++mi) {
                int p = (wv * 2 + mi) * 16 + r + ky;
                int off = p * 128 + ((q ^ (p & 7)) << 4);
                ah[mi] = *(const short8*)(sm + off);
                al[mi] = *(const short8*)(sm + (off ^ 64));
            }
            // term-major: 6 independent MFMAs between dependent uses
            #pragma unroll
            for (int ni = 0; ni < 3; ++ni)
                #pragma unroll
                for (int mi = 0; mi < 2; ++mi)
                    acc[mi][ni] = __builtin_amdgcn_mfma_f32_16x16x32_bf16(ah[mi], Bh[cur][ni], acc[mi][ni], 0, 0, 0);
            #pragma unroll
            for (int ni = 0; ni < 3; ++ni)
                #pragma unroll
                for (int mi = 0; mi < 2; ++mi)
                    acc[mi][ni] = __builtin_amdgcn_mfma_f32_16x16x32_bf16(ah[mi], Bl[cur][ni], acc[mi][ni], 0, 0, 0);
            #pragma unroll
            for (int ni = 0; ni < 3; ++ni)
                #pragma unroll
                for (int mi = 0; mi < 2; ++mi)
                    acc[mi][ni] = __builtin_amdgcn_mfma_f32_16x16x32_bf16(al[mi], Bh[cur][ni], acc[mi][ni], 0, 0, 0);
        }
        __syncthreads();
        if (cs < 8) {
            stage(cs + 1);
            __syncthreads();
        }
    }

    // epilogue: bias + leaky store, accumulating per-thread t-partials
    float psum[3] = {0.f, 0.f, 0.f};
    #pragma unroll
    for (int ni = 0; ni < 3; ++ni) {
        int n = (nt * 3 + ni) * 16 + r;
        if (n >= NFB) continue;
        float bi0 = bia[n];
        #pragma unroll
        for (int mi = 0; mi < 2; ++mi) {
            int tb = t0 + (wv * 2 + mi) * 16 + q * 4;
            #pragma unroll
            for (int j = 0; j < 4; ++j) {
                int t = tb + j;
                if (t < NANG) {
                    float v = acc[mi][ni][j] + bi0;
                    v = (v >= 0.f) ? v : 0.1f * v;
                    sp2[((size_t)b * NANG + t) * NFB + n] = v;
                    psum[ni] += v;
                }
            }
        }
    }
    // reduce psum over q (shfl) then over waves (LDS), write part[b][tt][f]
    float* wred = (float*)sm;                 // 4 waves x 3 ni x 16 r
    #pragma unroll
    for (int ni = 0; ni < 3; ++ni) {
        float s = psum[ni];
        s += __shfl_down(s, 32, 64);
        s += __shfl_down(s, 16, 64);
        if (q == 0) wred[(wv * 3 + ni) * 16 + r] = s;
    }
    __syncthreads();
    if (tid < 48) {
        int ni = tid / 16, rr = tid % 16;
        float tot = wred[(0 * 3 + ni) * 16 + rr] + wred[(1 * 3 + ni) * 16 + rr]
                  + wred[(2 * 3 + ni) * 16 + rr] + wred[(3 * 3 + ni) * 16 + rr];
        int n = (nt * 3 + ni) * 16 + rr;
        if (n < NFB) part[((size_t)b * 3 + tt) * NFB + n] = tot;
    }
}

// ---------------------------------------------------------------------------
// FC: z (b, 64 pix, 257 f) NHWC f32 -> zfc (b, f, 32)
// ---------------------------------------------------------------------------
__global__ __launch_bounds__(256) void fc_kernel(
    const float* __restrict__ z, const float* __restrict__ fw,
    const float* __restrict__ fb, float* __restrict__ zfc)
{
    int bid = blockIdx.x;
    int ftile = bid % 33;
    int b = bid / 33;
    int j = threadIdx.x & 31;
    int f = ftile * 8 + (threadIdx.x >> 5);
    if (f >= 257) return;
    const float* zb = z + (size_t)b * 16448;
    float a = fb[j];
    #pragma unroll 8
    for (int s = 0; s < 64; ++s) a = fmaf(zb[s * 257 + f], fw[j * 64 + s], a);
    zfc[((size_t)b * 257 + f) * 32 + j] = a;
}

// ---------------------------------------------------------------------------
// Per-thread 4x4 Hermitian eigh (complex Jacobi, f64) -> Re(Un Un^H)
// 256-thread blocks for wave packing (identical per-thread math).
// ---------------------------------------------------------------------------
__global__ __launch_bounds__(256) void eigh_kernel(const float* __restrict__ z, double* __restrict__ rp)
{
    int idx = blockIdx.x * 256 + threadIdx.x;
    if (idx >= NB * NFB) return;
    const float* zr = z + (size_t)idx * 32;
    double Ar[4][4], Ai[4][4], Vr[4][4], Vi[4][4];
    #pragma unroll
    for (int m = 0; m < 4; ++m)
        #pragma unroll
        for (int n = 0; n < 4; ++n) {
            Ar[m][n] = 0.5 * ((double)zr[m * 8 + n] + (double)zr[n * 8 + m]);
            Ai[m][n] = 0.5 * ((double)zr[m * 8 + n + 4] - (double)zr[n * 8 + m + 4]);
            Vr[m][n] = (m == n) ? 1.0 : 0.0;
            Vi[m][n] = 0.0;
        }
    #pragma unroll
    for (int m = 0; m < 4; ++m) Ar[m][m] += 1e-5;

    for (int sweep = 0; sweep < 8; ++sweep) {
        #pragma unroll
        for (int p = 0; p < 3; ++p)
            #pragma unroll
            for (int qq = p + 1; qq < 4; ++qq) {
                double apr = Ar[p][qq], api = Ai[p][qq];
                double rmod = sqrt(apr * apr + api * api);
                if (rmod < 1e-300) continue;
                double cph = apr / rmod, sph = api / rmod;
                double tau = (Ar[qq][qq] - Ar[p][p]) / (2.0 * rmod);
                double t = (tau >= 0.0) ? (-1.0 / (tau + sqrt(1.0 + tau * tau)))
                                        : (1.0 / (-tau + sqrt(1.0 + tau * tau)));
                double c = 1.0 / sqrt(1.0 + t * t);
                double s = t * c;
                double wr = s * cph, wi = s * sph;
                #pragma unroll
                for (int i = 0; i < 4; ++i) {
                    double xr = Ar[i][p], xi = Ai[i][p];
                    double yr = Ar[i][qq], yi = Ai[i][qq];
                    Ar[i][p] = c * xr + (wr * yr + wi * yi);
                    Ai[i][p] = c * xi + (wr * yi - wi * yr);
                    Ar[i][qq] = c * yr - (wr * xr - wi * xi);
                    Ai[i][qq] = c * yi - (wr * xi + wi * xr);
                }
                #pragma unroll
                for (int i = 0; i < 4; ++i) {
                    double xr = Ar[p][i], xi = Ai[p][i];
                    double yr = Ar[qq][i], yi = Ai[qq][i];
                    Ar[p][i] = c * xr + (wr * yr - wi * yi);
                    Ai[p][i] = c * xi + (wr * yi + wi * yr);
                    Ar[qq][i] = c * yr - (wr * xr + wi * xi);
                    Ai[qq][i] = c * yi - (wr * xi - wi * xr);
                }
                #pragma unroll
                for (int i = 0; i < 4; ++i) {
                    double xr = Vr[i][p], xi = Vi[i][p];
                    double yr = Vr[i][qq], yi = Vi[i][qq];
                    Vr[i][p] = c * xr + (wr * yr + wi * yi);
                    Vi[i][p] = c * xi + (wr * yi - wi * yr);
                    Vr[i][qq] = c * yr - (wr * xr - wi * xi);
                    Vi[i][qq] = c * yi - (wr * xi + wi * xr);
                }
            }
    }
    double ev[4] = {Ar[0][0], Ar[1][1], Ar[2][2], Ar[3][3]};
    int i0 = 0;
    #pragma unroll
    for (int k = 1; k < 4; ++k) if (ev[k] < ev[i0]) i0 = k;
    int i1 = (i0 == 0) ? 1 : 0;
    #pragma unroll
    for (int k = 0; k < 4; ++k) if (k != i0 && ev[k] < ev[i1]) i1 = k;
    double* o = rp + (size_t)idx * 16;
    #pragma unroll
    for (int m = 0; m < 4; ++m)
        #pragma unroll
        for (int n = 0; n < 4; ++n)
            o[m * 4 + n] = Vr[m][i0] * Vr[n][i0] + Vi[m][i0] * Vi[n][i0]
                         + Vr[m][i1] * Vr[n][i1] + Vi[m][i1] * Vi[n][i1];
}

// ---------------------------------------------------------------------------
// MUSIC spectrum -> unified mu (b, t=a+1 in 362, 9 sections of [hi32|lo32]).
// Symmetric 10-term quadratic form (P symmetric; off-diag pre-doubled) +
// all-loads-prefetched (8 in-flight per thread) for MLP.  [round-12 optimum]
// ---------------------------------------------------------------------------
__global__ __launch_bounds__(256) void music_kernel(
    const float4* __restrict__ svr, const float4* __restrict__ svi,
    const double* __restrict__ rp, u16* __restrict__ mu)
{
    __shared__ double P[32][10];
    __shared__ float T[32][33];
    int bid = blockIdx.x;
    int at = bid % 12; bid /= 12;
    int ft = bid % 9;
    int b = bid / 9;
    int f0 = ft * 32, a0 = at * 32;
    int tid = threadIdx.x;
    // stage P compressed: j -> (m,n) pairs; off-diag doubled
    for (int i = tid; i < 32 * 10; i += 256) {
        int fi = i / 10, j = i % 10;
        const int mm[10] = {0, 1, 2, 3, 0, 0, 0, 1, 1, 2};
        const int nn[10] = {0, 1, 2, 3, 1, 2, 3, 2, 3, 3};
        int f = f0 + fi;
        double v = 0.0;
        if (f < 257) {
            v = rp[((size_t)b * 257 + f) * 16 + mm[j] * 4 + nn[j]];
            if (j >= 4) v += v;
        }
        P[fi][j] = v;
    }
    __syncthreads();
    int asub = tid & 31, fsub = tid >> 5;
    int a = a0 + asub;
    bool av = (a < 360);
    // prefetch ALL loads (8 independent) before any f64 compute
    float4 u[4], w[4];
    #pragma unroll
    for (int k2 = 0; k2 < 4; ++k2) {
        int f = f0 + fsub + 8 * k2;
        u[k2] = (float4){0.f, 0.f, 0.f, 0.f};
        w[k2] = (float4){0.f, 0.f, 0.f, 0.f};
        if (av && f < 257) {
            u[k2] = svr[((size_t)b * 257 + f) * 360 + a];
            w[k2] = svi[((size_t)b * 257 + f) * 360 + a];
        }
    }
    #pragma unroll
    for (int k2 = 0; k2 < 4; ++k2) {
        int fl = fsub + 8 * k2;
        double ua[4] = {u[k2].x, u[k2].y, u[k2].z, u[k2].w};
        double wa[4] = {w[k2].x, w[k2].y, w[k2].z, w[k2].w};
        const double* Pf = P[fl];
        const int mm[10] = {0, 1, 2, 3, 0, 0, 0, 1, 1, 2};
        const int nn[10] = {0, 1, 2, 3, 1, 2, 3, 2, 3, 3};
        double den = 0.0;
        #pragma unroll
        for (int j = 0; j < 10; ++j)
            den += Pf[j] * (ua[mm[j]] * ua[nn[j]] - wa[mm[j]] * wa[nn[j]]);
        T[asub][fl] = (float)(1.0 / fmax(den, 1e-6));
    }
    __syncthreads();
    int sec0 = f0 >> 5;
    #pragma unroll
    for (int p = 0; p < 4; ++p) {
        int row = p * 8 + (tid >> 5);
        int fc = tid & 31;
        int a2 = a0 + row;
        if (a2 < 360) {
            float v = T[row][fc];
            u16* d = mu + ((size_t)b * 362 + a2 + 1) * 576 + (size_t)sec0 * 64 + fc;
            u16 hh = f2bf(v);
            d[0] = hh;
            d[32] = f2bf(v - bf2f(hh));
        }
    }
}

// ---------------------------------------------------------------------------
// attention finish (mean -> MLP -> sigmoid); part has 3 chunks per b.
// h-dot parallelized: 16 h x 16 threads.
// ---------------------------------------------------------------------------
__global__ __launch_bounds__(256) void attn_finish(
    const float* __restrict__ part, const float* __restrict__ w1,
    const float* __restrict__ w2, float* __restrict__ att)
{
    __shared__ float ys[257];
    __shared__ float hp[16][17];
    __shared__ float hs[16];
    int b = blockIdx.x;
    int tid = threadIdx.x;
    for (int f = tid; f < 257; f += 256) {
        float s = part[((size_t)b * 3 + 0) * 257 + f]
                + part[((size_t)b * 3 + 1) * 257 + f]
                + part[((size_t)b * 3 + 2) * 257 + f];
        ys[f] = s * (1.0f / 360.0f);
    }
    __syncthreads();
    {
        int h = tid >> 4, seg = tid & 15;
        float p = 0.f;
        for (int c = seg; c < 257; c += 16)
            p = fmaf(ys[c], w1[(size_t)h * 257 + c], p);
        hp[h][seg] = p;
    }
    __syncthreads();
    if (tid < 16) {
        float s = 0.f;
        #pragma unroll
        for (int k = 0; k < 16; ++k) s += hp[tid][k];
        hs[tid] = fmaxf(s, 0.f);
    }
    __syncthreads();
    for (int o = tid; o < 257; o += 256) {
        float a = 0.f;
        #pragma unroll
        for (int j = 0; j < 16; ++j) a = fmaf(hs[j], w2[(size_t)o * 16 + j], a);
        att[(size_t)b * 257 + o] = 1.0f / (1.0f + expf(-a));
    }
}

// ---------------------------------------------------------------------------
// conv1d 257->1 over att-weighted sp2(b,t,f), sigmoid -> outS (b,360)
// ---------------------------------------------------------------------------
__global__ __launch_bounds__(256) void convs1_kernel(
    const float* __restrict__ sp2, const float* __restrict__ att,
    const float* __restrict__ w, const float* __restrict__ bb,
    float* __restrict__ outS)
{
    int bid = blockIdx.x;
    int tt = bid % 90;
    int b = bid / 90;
    int wv = threadIdx.x >> 6, l = threadIdx.x & 63;
    int t = tt * 4 + wv;
    float s = 0.f;
    for (int f = l; f < 257; f += 64) {
        float av = att[(size_t)b * 257 + f];
        float w0 = w[f * 3] * av, w1 = w[f * 3 + 1] * av, w2 = w[f * 3 + 2] * av;
        const float* col = sp2 + (size_t)b * 360 * 257 + f;
        if (t > 0)   s = fmaf(w0, col[(size_t)(t - 1) * 257], s);
        s = fmaf(w1, col[(size_t)t * 257], s);
        if (t < 359) s = fmaf(w2, col[(size_t)(t + 1) * 257], s);
    }
    #pragma unroll
    for (int off = 32; off > 0; off >>= 1) s += __shfl_down(s, off, 64);
    if (l == 0) outS[(size_t)b * 360 + t] = 1.0f / (1.0f + expf(-(s + bb[0])));
}

// ---------------------------------------------------------------------------
// top-5 soft-argmax, wave-parallel (strict >, index asc tie-break)
// ---------------------------------------------------------------------------
__global__ __launch_bounds__(64) void doa_kernel(const float* __restrict__ spec, float* __restrict__ doa)
{
    int b = blockIdx.x;
    int l = threadIdx.x;
    const float* s = spec + (size_t)b * NANG;
    float v[6];
    #pragma unroll
    for (int j = 0; j < 6; ++j) {
        int idx = l + 64 * j;
        v[j] = (idx < NANG) ? s[idx] : -3.4e38f;
    }
    float wvv[5]; int wii[5];
    #pragma unroll
    for (int k = 0; k < 5; ++k) {
        float bv = v[0]; int bj = 0;
        #pragma unroll
        for (int j = 1; j < 6; ++j)
            if (v[j] > bv) { bv = v[j]; bj = j; }
        int bi = l + 64 * bj;
        #pragma unroll
        for (int off = 1; off < 64; off <<= 1) {
            float ov = __shfl_xor(bv, off, 64);
            int oi = __shfl_xor(bi, off, 64);
            if (ov > bv || (ov == bv && oi < bi)) { bv = ov; bi = oi; }
        }
        wvv[k] = bv; wii[k] = bi;
        if ((bi & 63) == l) {
            int j = bi >> 6;
            #pragma unroll
            for (int jj = 0; jj < 6; ++jj)
                if (jj == j) v[jj] = -3.4e38f;
        }
    }
    if (l == 0) {
        float m = wvv[0];
        float wsum = 0.f, asum = 0.f;
        #pragma unroll
        for (int k = 0; k < 5; ++k) {
            float e = expf(20.0f * (wvv[k] - m));
            wsum += e;
            asum += e * (float)wii[k];
        }
        doa[b] = asum / wsum;
    }
}

// ---------------------------------------------------------------------------
extern "C" void kernel_launch(void* const* d_in, const int* in_sizes, int n_in,
                              void* d_out, int out_size, void* d_ws, size_t ws_size,
                              hipStream_t stream)
{
    const float* X    = (const float*)d_in[0];
    const float* svr  = (const float*)d_in[1];
    const float* svi  = (const float*)d_in[2];
    const float* c1w  = (const float*)d_in[4];
    const float* c2w  = (const float*)d_in[5];
    const float* c3w  = (const float*)d_in[6];
    const float* c4w  = (const float*)d_in[7];
    const float* fcw  = (const float*)d_in[8];
    const float* fcb  = (const float*)d_in[9];
    const float* s2w  = (const float*)d_in[10];
    const float* s2b  = (const float*)d_in[11];
    const float* s1w  = (const float*)d_in[12];
    const float* s1b  = (const float*)d_in[13];
    const float* caw1 = (const float*)d_in[14];
    const float* caw2 = (const float*)d_in[15];
    const float* bn1g = (const float*)d_in[16]; const float* bn1b = (const float*)d_in[17];
    const float* bn1m = (const float*)d_in[18]; const float* bn1v = (const float*)d_in[19];
    const float* bn2g = (const float*)d_in[20]; const float* bn2b = (const float*)d_in[21];
    const float* bn2m = (const float*)d_in[22]; const float* bn2v = (const float*)d_in[23];
    const float* bn3g = (const float*)d_in[24]; const float* bn3b = (const float*)d_in[25];
    const float* bn3m = (const float*)d_in[26]; const float* bn3v = (const float*)d_in[27];
    const float* bn4g = (const float*)d_in[28]; const float* bn4b = (const float*)d_in[29];
    const float* bn4m = (const float*)d_in[30]; const float* bn4v = (const float*)d_in[31];

    char* wsb = (char*)d_ws;
    // region A (time-disjoint: xp -> c3 -> mu)
    u16* xp = (u16*)(wsb + 0);               // 34,611,200 B (64x130x130x32B)
    u16* c3 = (u16*)(wsb + 0);               // 18,939,904 B (64x34x34x256B)
    u16* mu = (u16*)(wsb + 0);               // 26,689,536 B (64x362x1152B)
    // region B (c2 -> {zbuf, zfc, rp, sp2, part, att})
    const size_t Bb = 34611200;
    u16*   c2  = (u16*)(wsb + Bb);           // 71,368,704 B (64x66x66x256B)
    float*  zbuf = (float*)(wsb + Bb);
    float*  zfc  = (float*)(wsb + Bb + 4210688);
    double* rp   = (double*)(wsb + Bb + 6316032);
    float*  sp2  = (float*)(wsb + Bb + 8421376);
    float*  part = (float*)(wsb + Bb + 32106496);
    float*  att  = (float*)(wsb + Bb + 32501248);
    // region C (persistent small)
    const size_t Cb = Bb + 71368704;
    u16* c4  = (u16*)(wsb + Cb);             // 5,308,416 B (64x18x18x256B)
    u16* bp1 = (u16*)(wsb + Cb + 5308416);
    u16* bp2 = (u16*)(wsb + Cb + 5382144);
    u16* bp3 = (u16*)(wsb + Cb + 5529600);
    u16* bp4 = (u16*)(wsb + Cb + 5677056);
    u16* bp5 = (u16*)(wsb + Cb + 6414336);
    float* bns = (float*)(wsb + Cb + 7409664);

    float* outD = (float*)d_out;
    float* outS = (float*)d_out + 64;

    // --- fused prep (bnprep + all bpacks + xpack) + fused init zpads ---
    prep_kernel<<<8825, 256, 0, stream>>>(
        X, xp, c1w, bp1, c2w, bp2, c3w, bp3, c4w, bp4, s2w, bp5,
        bn1g, bn1b, bn1m, bn1v, bn2g, bn2b, bn2m, bn2v,
        bn3g, bn3b, bn3m, bn3v, bn4g, bn4b, bn4m, bn4v, bns);
    zpad_init<<<2048, 256, 0, stream>>>((u32*)c2, (u32*)c4);

    // --- conv1 (3-term) ---
    conv_c1<<<64 * 64, 256, 0, stream>>>(xp, bp1, bns, bns + 512, c2);
    zpad<<<2112, 256, 0, stream>>>((u32*)c3, 64, 34, 34, 64, 1);   // A region free now
    // --- conv2 (3-term) ---
    conv_gemm<64, 64, 64, 2, 4, 2, 0, 4>
        <<<dim3(64 * 32, 1), 256, 0, stream>>>(c2, bp2, bns + 1024, bns + 1536, c3, nullptr);
    // --- conv3 (3-term) ---
    conv_gemm<32, 32, 64, 4, 4, 2, 0, 4>
        <<<dim3(64 * 8, 1), 256, 0, stream>>>(c3, bp3, bns + 2048, bns + 2560, c4, nullptr);
    zpad<<<144, 256, 0, stream>>>((u32*)mu, 64, 362, 1, 288, 0);   // A region free now
    // --- conv4 (3-term) -> z f32 (b,8,8,257) ---
    conv_gemm<16, 16, 257, 8, 4, 2, 1, 20>
        <<<dim3(64 * 2, 5), 256, 0, stream>>>(c4, bp4, bns + 3072, bns + 3584, nullptr, zbuf);

    fc_kernel<<<64 * 33, 256, 0, stream>>>(zbuf, fcw, fcb, zfc);
    eigh_kernel<<<65, 256, 0, stream>>>(zfc, rp);
    music_kernel<<<64 * 108, 256, 0, stream>>>((const float4*)svr, (const float4*)svi, rp, mu);
    // --- convs2 (3-term, +fused attention partial sums) -> sp2, part ---
    convs2_gemm<<<dim3(64 * 3, 6), 256, 0, stream>>>(mu, bp5, s2b, sp2, part);

    attn_finish<<<64, 256, 0, stream>>>(part, caw1, caw2, att);
    convs1_kernel<<<64 * 90, 256, 0, stream>>>(sp2, att, s1w, s1b, outS);
    doa_kernel<<<64, 64, 0, stream>>>(outS, outD);
}

// Round 16
// 366.738 us; speedup vs baseline: 1.0806x; 1.0183x over previous
//
#include <hip/hip_runtime.h>

typedef unsigned short u16;
typedef unsigned int u32;
typedef short short8 __attribute__((ext_vector_type(8)));
typedef float f32x4 __attribute__((ext_vector_type(4)));

#define NB 64
#define NFB 257
#define NANG 360

template<int V> struct IC { static constexpr int value = V; };

__device__ __forceinline__ u16 f2bf(float x) {
    u32 u = __float_as_uint(x);
    u = (u + 0x7fffu + ((u >> 16) & 1u)) >> 16;
    return (u16)u;
}
__device__ __forceinline__ float bf2f(u16 h) { return __uint_as_float(((u32)h) << 16); }

// async global->LDS, 16B per lane; LDS dest = wave-uniform base + lane*16
__device__ __forceinline__ void glds16(const void* g, void* l3) {
    __builtin_amdgcn_global_load_lds(
        (const __attribute__((address_space(1))) void*)g,
        (__attribute__((address_space(3))) void*)l3, 16, 0, 0);
}

// ---------------------------------------------------------------------------
// Unified activation layout: per pixel, (C/32) sections of 128 B:
//   [hi ch0-31 (64B) | lo ch0-31 (64B)] [hi ch32-63 | lo ch32-63] ...
// NUMERICS NOTE (round-10 failure): all convs must keep the full 3-term
// bf16 split (Ah*Bh + Ah*Bl + Al*Bh ~ f32 quality).  2-term (B rounded to
// bf16) produced 0.2%/layer error that flipped near-degenerate eigenvector
// subspaces in eigh -> 1/denom chaos -> doa absmax 171.  Do not retry.
// PERF NOTE (rounds 12/13): music is occupancy/latency-bound.  8-load
// prefetch @ VGPR 40 / 56% occ is the local optimum; 16-load prefetch
// (VGPR 76, 28% occ) REGRESSED 69.5 -> 83 us.  Do not deepen prefetch.
// STAGING (rounds 15/16): conv_gemm/convs2 stage via global_load_lds
// width=16 with pre-swizzled SOURCE + linear LDS dest; conv_c1 stages two
// linear 16B/pixel planes (hi/lo) -- 16 consecutive pixels per quarter =
// 2-way bank aliasing = free.
// ---------------------------------------------------------------------------

// ---------------------------------------------------------------------------
// Fused prep: bnprep(4) | bpack1(6) | bpack c2(36) c3(36) c4(180) s2(243) |
// xpack(8320).  One launch, branch by block range.
// ---------------------------------------------------------------------------
__device__ __forceinline__ void bpack_body(
    const float* __restrict__ w, u16* __restrict__ Bp,
    int CREAL, int OCREAL, int NT, int KCC, int NFTOT, int i)
{
    int total = NT * KCC * 2 * NFTOT * 64;
    if (i >= total) return;
    int lane = i & 63;
    int t = i >> 6;
    int nf = t % NFTOT;
    int th = t / NFTOT;
    int h = th & 1;
    int chunk = th >> 1;
    int s = chunk / KCC, kc = chunk % KCC;
    int n = nf * 16 + (lane & 15);
    int k0 = kc * 32 + (lane >> 4) * 8;
    u16 o8[8];
    #pragma unroll
    for (int e = 0; e < 8; ++e) {
        int k = k0 + e;
        float v = 0.f;
        if (k < CREAL && n < OCREAL) v = w[((size_t)n * CREAL + k) * NT + s];
        u16 hh = f2bf(v);
        o8[e] = (h == 0) ? hh : f2bf(v - bf2f(hh));
    }
    u16* d = Bp + (size_t)i * 8;
    #pragma unroll
    for (int e = 0; e < 8; ++e) d[e] = o8[e];
}

__global__ __launch_bounds__(256) void prep_kernel(
    const float* __restrict__ X, u16* __restrict__ xp,
    const float* __restrict__ c1w, u16* __restrict__ bp1,
    const float* __restrict__ c2w, u16* __restrict__ bp2,
    const float* __restrict__ c3w, u16* __restrict__ bp3,
    const float* __restrict__ c4w, u16* __restrict__ bp4,
    const float* __restrict__ s2w, u16* __restrict__ bp5,
    const float* g1, const float* b1, const float* m1, const float* v1,
    const float* g2, const float* b2, const float* m2, const float* v2,
    const float* g3, const float* b3, const float* m3, const float* v3,
    const float* g4, const float* b4, const float* m4, const float* v4,
    float* __restrict__ bns)
{
    __shared__ float Xs[8][132];
    int blk = blockIdx.x;
    int tid = threadIdx.x;
    if (blk < 4) {
        int L = blk;
        const float* gs[4] = {g1, g2, g3, g4};
        const float* bs[4] = {b1, b2, b3, b4};
        const float* ms[4] = {m1, m2, m3, m4};
        const float* vs[4] = {v1, v2, v3, v4};
        int n = (L == 3) ? 257 : 64;
        float* sc = bns + L * 1024;
        float* bi = sc + 512;
        for (int i = tid; i < n; i += 256) {
            float s = gs[L][i] * rsqrtf(vs[L][i] + 1e-5f);
            sc[i] = s;
            bi[i] = bs[L][i] - ms[L][i] * s;
        }
    } else if (blk < 10) {
        int i = (blk - 4) * 256 + tid;
        if (i < 3 * 2 * 4 * 64) {
            int lane = i & 63;
            int t = i >> 6;
            int nf = t % 4;
            int th = t / 4;
            int h = th & 1;
            int ky = th >> 1;
            int n = nf * 16 + (lane & 15);
            int q = lane >> 4;
            u16 o8[8];
            #pragma unroll
            for (int e = 0; e < 8; ++e) {
                float v = (q < 3) ? c1w[((size_t)(n * 8 + e) * 3 + ky) * 3 + q] : 0.f;
                u16 hh = f2bf(v);
                o8[e] = (h == 0) ? hh : f2bf(v - bf2f(hh));
            }
            u16* d = bp1 + (size_t)i * 8;
            #pragma unroll
            for (int e = 0; e < 8; ++e) d[e] = o8[e];
        }
    } else if (blk < 46) {
        bpack_body(c2w, bp2, 64, 64, 9, 2, 4, (blk - 10) * 256 + tid);
    } else if (blk < 82) {
        bpack_body(c3w, bp3, 64, 64, 9, 2, 4, (blk - 46) * 256 + tid);
    } else if (blk < 262) {
        bpack_body(c4w, bp4, 64, 257, 9, 2, 20, (blk - 82) * 256 + tid);
    } else if (blk < 505) {
        bpack_body(s2w, bp5, 257, 257, 3, 9, 18, (blk - 262) * 256 + tid);
    } else {
        int row = blk - 505;
        int prow = row % 130;
        int b = row / 130;
        bool inr = (prow >= 1 && prow <= 128);
        for (int i = tid; i < 8 * 130; i += 256) {
            int c = i / 130, pcol = i % 130;
            float v = 0.f;
            if (inr && pcol >= 1 && pcol <= 128)
                v = X[(((size_t)b * 8 + c) * 128 + (prow - 1)) * 128 + (pcol - 1)];
            Xs[c][pcol] = v;
        }
        __syncthreads();
        for (int p = tid; p < 130; p += 256) {
            short8 h8, l8;
            #pragma unroll
            for (int c = 0; c < 8; ++c) {
                float f = Xs[c][p];
                u16 hh = f2bf(f);
                h8[c] = (short)hh;
                l8[c] = (short)f2bf(f - bf2f(hh));
            }
            size_t o = (((size_t)b * 130 + prow) * 130 + p) * 16;
            *(short8*)(xp + o) = h8;
            *(short8*)(xp + o + 8) = l8;
        }
    }
}

// ---------------------------------------------------------------------------
// Zero borders: generic + fused-init (c2 + c4) variants.
// ---------------------------------------------------------------------------
__device__ __forceinline__ void zpad_body(u32* buf, int Hp, int Wp, int wpp, int doCols, long idx)
{
    int perB = 2 * Wp + (doCols ? 2 * (Hp - 2) : 0);
    int w = (int)(idx % wpp);
    long t = idx / wpp;
    int p = (int)(t % perB);
    int b = (int)(t / perB);
    int row, col;
    if (p < Wp) { row = 0; col = p; }
    else if (p < 2 * Wp) { row = Hp - 1; col = p - Wp; }
    else { int pp = p - 2 * Wp; row = 1 + (pp >> 1); col = (pp & 1) ? (Wp - 1) : 0; }
    buf[(((size_t)b * Hp + row) * Wp + col) * (size_t)wpp + w] = 0;
}

__global__ __launch_bounds__(256) void zpad(
    u32* buf, int Bn, int Hp, int Wp, int wpp, int doCols)
{
    int perB = 2 * Wp + (doCols ? 2 * (Hp - 2) : 0);
    long total = (long)Bn * perB * wpp;
    for (long idx = blockIdx.x * 256L + threadIdx.x; idx < total; idx += (long)gridDim.x * 256)
        zpad_body(buf, Hp, Wp, wpp, doCols, idx);
}

__global__ __launch_bounds__(256) void zpad_init(u32* c2b, u32* c4b)
{
    const long T1 = 64L * 260 * 64;   // c2: perB = 2*66 + 2*64
    const long T2 = 64L * 68 * 64;    // c4: perB = 2*18 + 2*16
    for (long idx = blockIdx.x * 256L + threadIdx.x; idx < T1 + T2; idx += (long)gridDim.x * 256) {
        if (idx < T1) zpad_body(c2b, 66, 66, 64, 1, idx);
        else          zpad_body(c4b, 18, 18, 64, 1, idx - T1);
    }
}

// ---------------------------------------------------------------------------
// conv1 dedicated: C=8, K packs 4 pixels x 8 ch (kx in K).  3 chunks.
// Full 3-term split; term-major interleave; in-register 2x2 pooling.
// Staging via global_load_lds into two linear 16B/pixel planes (hi, lo).
// ---------------------------------------------------------------------------
__global__ __launch_bounds__(256) void conv_c1(
    const u16* __restrict__ A, const u16* __restrict__ Bp,
    const float* __restrict__ esc, const float* __restrict__ ebi,
    u16* __restrict__ O)
{
    constexpr int Wst = 130, Hp = 130;
    constexpr int SROWS = 5;                 // 2 rows + 2 halo + 1 wrap-guard
    constexpr int SPIX = SROWS * Wst;        // 650
    constexpr int PLANE = SPIX * 16;         // 10400 B per plane
    __shared__ __align__(16) char sm[2 * PLANE];

    int bid = blockIdx.x;
    int ytile = bid % 64;
    int b = bid / 64;
    int y0 = ytile * 2;
    int tid = threadIdx.x;
    int wv = tid >> 6;
    int l = tid & 63;
    int r = l & 15, q = l >> 4;

    // async stage: pixel pix hi -> sm[pix*16], lo -> sm[PLANE + pix*16].
    // guard-row bytes (prow==Hp for the last tile) land in allocated
    // workspace and are only ever multiplied by exact-zero weights.
    {
        constexpr int WIT = (SPIX + 63) / 64;    // 11
        for (int it2 = wv; it2 < WIT; it2 += 4) {
            int pix = it2 * 64 + l;
            int prow = y0 + pix / Wst, pcol = pix % Wst;
            const u16* src = A + (((size_t)b * Hp + prow) * Wst + pcol) * 16;
            if (pix < SPIX) {
                glds16(src, sm + it2 * 1024 + l * 16);
                glds16(src + 8, sm + PLANE + it2 * 1024 + l * 16);
            }
        }
    }
    __syncthreads();

    f32x4 acc[4][4] = {};

    #pragma unroll
    for (int ky = 0; ky < 3; ++ky) {
        short8 bh[4], bl[4];
        #pragma unroll
        for (int ni = 0; ni < 4; ++ni) {
            const u16* bt = Bp + ((size_t)(ky * 2) * 4 + ni) * 512 + l * 8;
            bh[ni] = *(const short8*)bt;
            bl[ni] = *(const short8*)(bt + 4 * 512);
        }
        short8 ah[4], al[4];
        #pragma unroll
        for (int mi = 0; mi < 4; ++mi) {
            int pf = wv * 2 + (mi >> 1);
            int y = mi & 1;
            int p = (y + ky) * Wst + pf * 16 + r + q;   // wrap lands on guard row, zero-weighted
            ah[mi] = *(const short8*)(sm + p * 16);
            al[mi] = *(const short8*)(sm + PLANE + p * 16);
        }
        #pragma unroll
        for (int ni = 0; ni < 4; ++ni)
            #pragma unroll
            for (int mi = 0; mi < 4; ++mi)
                acc[mi][ni] = __builtin_amdgcn_mfma_f32_16x16x32_bf16(ah[mi], bh[ni], acc[mi][ni], 0, 0, 0);
        #pragma unroll
        for (int ni = 0; ni < 4; ++ni)
            #pragma unroll
            for (int mi = 0; mi < 4; ++mi)
                acc[mi][ni] = __builtin_amdgcn_mfma_f32_16x16x32_bf16(ah[mi], bl[ni], acc[mi][ni], 0, 0, 0);
        #pragma unroll
        for (int ni = 0; ni < 4; ++ni)
            #pragma unroll
            for (int mi = 0; mi < 4; ++mi)
                acc[mi][ni] = __builtin_amdgcn_mfma_f32_16x16x32_bf16(al[mi], bh[ni], acc[mi][ni], 0, 0, 0);
    }

    // in-register BN+ReLU+2x2 pool -> unified c2 (66x66, 2 sections)
    #pragma unroll
    for (int ni = 0; ni < 4; ++ni) {
        int oc = ni * 16 + r;
        float sc0 = esc[oc], bi0 = ebi[oc];
        #pragma unroll
        for (int pi = 0; pi < 2; ++pi) {
            int pf = wv * 2 + pi;
            #pragma unroll
            for (int k = 0; k < 2; ++k) {
                float m = -3.4e38f;
                #pragma unroll
                for (int dmi = 0; dmi < 2; ++dmi)
                    #pragma unroll
                    for (int dj = 0; dj < 2; ++dj)
                        m = fmaxf(m, fmaf(acc[2 * pi + dmi][ni][2 * k + dj], sc0, bi0));
                m = fmaxf(m, 0.f);
                int x2 = pf * 8 + q * 2 + k;
                size_t base = (((size_t)b * 66 + (y0 / 2 + 1)) * 66 + (x2 + 1)) * 128;
                u16* d = O + base + ((oc >> 5) << 6) + (oc & 31);
                u16 hh = f2bf(m);
                d[0] = hh;
                d[32] = f2bf(m - bf2f(hh));
            }
        }
    }
}

// ---------------------------------------------------------------------------
// Shift-GEMM conv (C=64) via MFMA bf16 3-term split.  Unified layout, CSECT=2,
// XOR-swizzled LDS (via pre-swizzled global_load_lds source), B prefetch,
// term-major interleave, in-register pooling.
// OUTMODE 0: BN+ReLU+pool2 -> unified NHWC;  OUTMODE 1: -> f32 NHWC
// ---------------------------------------------------------------------------
template<int H, int W, int OC, int R, int NF, int MFW, int OUTMODE, int NFTOT>
__global__ __launch_bounds__(256) void conv_gemm(
    const u16* __restrict__ A, const u16* __restrict__ Bp,
    const float* __restrict__ esc, const float* __restrict__ ebi,
    u16* __restrict__ O, float* __restrict__ Of)
{
    constexpr int Wst = W + 2, Hp = H + 2;
    constexpr int SROWS = R + 2;
    constexpr int SPIX = SROWS * Wst;
    constexpr int XF = W / 16;
    constexpr int HT = H / R;
    __shared__ __align__(16) char sm[SPIX * 128];

    int bid = blockIdx.x;
    int ytile = bid % HT;
    int b = bid / HT;
    int tid = threadIdx.x;
    int wv = tid >> 6;
    int l = tid & 63;
    int r = l & 15, q = l >> 4;
    int y0 = ytile * R;
    int nfg0 = blockIdx.y * NF;

    f32x4 acc[MFW][NF] = {};
    short8 Bh[2][NF], Bl[2][NF];

    auto loadB = [&](int buf, int chunk) {
        #pragma unroll
        for (int ni = 0; ni < NF; ++ni) {
            const u16* bt = Bp + ((size_t)(chunk * 2) * NFTOT + nfg0 + ni) * 512 + l * 8;
            Bh[buf][ni] = *(const short8*)bt;
            Bl[buf][ni] = *(const short8*)(bt + (size_t)NFTOT * 512);
        }
    };

    // async stage: LDS linear (it*1024 + lane*16); source pre-swizzled so
    // LDS slot s of pixel p holds global granule s^(p&7) -- identical layout
    // to the old XOR ds_write.  All pixels in-bounds (prow <= Hp-1 always).
    auto stage = [&](int cs) {
        constexpr int GRAN = SPIX * 8;           // 16B granules per phase
        constexpr int WIT = (GRAN + 63) / 64;
        for (int it2 = wv; it2 < WIT; it2 += 4) {
            int g = it2 * 64 + l;
            int pix = g >> 3, slot = g & 7;
            int srcg = slot ^ (pix & 7);
            int prow = y0 + pix / Wst, pcol = pix % Wst;
            const u16* src = A + (((size_t)b * Hp + prow) * Wst + pcol) * 128 + cs * 64 + srcg * 8;
            char* dst = sm + it2 * 1024 + l * 16;
            if (g < GRAN) glds16(src, dst);
        }
    };

    auto computePhase = [&](auto csc) {
        constexpr int cs = decltype(csc)::value;
        #pragma unroll
        for (int s = 0; s < 9; ++s) {
            int cur = (cs * 9 + s) & 1;            // compile-time (unrolled)
            if (s < 8) loadB(cur ^ 1, (s + 1) * 2 + cs);
            else if (cs == 0) loadB(cur ^ 1, 1);   // s=0 of section 1
            int ky = s / 3, kx = s % 3;
            short8 ah[MFW], al[MFW];
            #pragma unroll
            for (int mi = 0; mi < MFW; ++mi) {
                int pf = wv * (MFW / 2) + (mi >> 1);
                int y = (pf / XF) * 2 + (mi & 1);
                int xf = pf % XF;
                int p = (y + ky) * Wst + xf * 16 + kx + r;
                int off = p * 128 + ((q ^ (p & 7)) << 4);
                ah[mi] = *(const short8*)(sm + off);
                al[mi] = *(const short8*)(sm + (off ^ 64));
            }
            // term-major: NF*MFW independent MFMAs between dependent uses
            #pragma unroll
            for (int ni = 0; ni < NF; ++ni)
                #pragma unroll
                for (int mi = 0; mi < MFW; ++mi)
                    acc[mi][ni] = __builtin_amdgcn_mfma_f32_16x16x32_bf16(ah[mi], Bh[cur][ni], acc[mi][ni], 0, 0, 0);
            #pragma unroll
            for (int ni = 0; ni < NF; ++ni)
                #pragma unroll
                for (int mi = 0; mi < MFW; ++mi)
                    acc[mi][ni] = __builtin_amdgcn_mfma_f32_16x16x32_bf16(ah[mi], Bl[cur][ni], acc[mi][ni], 0, 0, 0);
            #pragma unroll
            for (int ni = 0; ni < NF; ++ni)
                #pragma unroll
                for (int mi = 0; mi < MFW; ++mi)
                    acc[mi][ni] = __builtin_amdgcn_mfma_f32_16x16x32_bf16(al[mi], Bh[cur][ni], acc[mi][ni], 0, 0, 0);
        }
    };

    stage(0);
    loadB(0, 0);   // chunk = s*2+cs
    __syncthreads();
    computePhase(IC<0>{});
    __syncthreads();
    stage(1);
    __syncthreads();
    computePhase(IC<1>{});

    // in-register BN+ReLU+2x2 pool epilogue
    #pragma unroll
    for (int ni = 0; ni < NF; ++ni) {
        int oc = (nfg0 + ni) * 16 + r;
        float sc0 = esc[oc], bi0 = ebi[oc];   // bns regions 512-padded: safe oc<320
        #pragma unroll
        for (int pi = 0; pi < MFW / 2; ++pi) {
            int pf = wv * (MFW / 2) + pi;
            int y2 = y0 / 2 + pf / XF;
            int xb = (pf % XF) * 8 + q * 2;
            #pragma unroll
            for (int k = 0; k < 2; ++k) {
                float m = -3.4e38f;
                #pragma unroll
                for (int dmi = 0; dmi < 2; ++dmi)
                    #pragma unroll
                    for (int dj = 0; dj < 2; ++dj)
                        m = fmaxf(m, fmaf(acc[2 * pi + dmi][ni][2 * k + dj], sc0, bi0));
                m = fmaxf(m, 0.f);
                int x2 = xb + k;
                if (OUTMODE == 0) {
                    size_t base = (((size_t)b * (H / 2 + 2) + y2 + 1) * (W / 2 + 2) + (x2 + 1)) * 128;
                    u16* d = O + base + ((oc >> 5) << 6) + (oc & 31);
                    u16 hh = f2bf(m);
                    d[0] = hh;
                    d[32] = f2bf(m - bf2f(hh));
                } else {
                    if (oc < OC)
                        Of[(((size_t)b * (H / 2) + y2) * (W / 2) + x2) * (size_t)OC + oc] = m;
                }
            }
        }
    }
}

// ---------------------------------------------------------------------------
// convs2 GEMM, t-split x3 (128 t/block), global_load_lds staging (source
// pre-swizzled, OOB rows clamped to zeroed pad row 361), term-major (3-term),
// FUSED attention partial sums -> part[b][3][257].
// A: mu unified (b,362,9x128B).  Out sp2 (b,360,257) f32.
// ---------------------------------------------------------------------------
__global__ __launch_bounds__(256) void convs2_gemm(
    const u16* __restrict__ A, const u16* __restrict__ Bp,
    const float* __restrict__ bia, float* __restrict__ sp2,
    float* __restrict__ part)
{
    constexpr int SPIX = 130;
    __shared__ __align__(16) char sm[SPIX * 128];

    int bid = blockIdx.x;
    int tt = bid % 3;
    int b = bid / 3;
    int nt = blockIdx.y;
    int t0 = tt * 128;
    int tid = threadIdx.x;
    int wv = tid >> 6;
    int l = tid & 63;
    int r = l & 15, q = l >> 4;

    f32x4 acc[2][3] = {};
    short8 Bh[2][3], Bl[2][3];

    auto loadB = [&](int buf, int chunk) {
        #pragma unroll
        for (int ni = 0; ni < 3; ++ni) {
            const u16* bt = Bp + ((size_t)(chunk * 2) * 18 + nt * 3 + ni) * 512 + l * 8;
            Bh[buf][ni] = *(const short8*)bt;
            Bl[buf][ni] = *(const short8*)(bt + 18 * 512);
        }
    };

    auto stage = [&](int cs) {
        constexpr int GRAN = SPIX * 8;           // 1040
        constexpr int WIT = (GRAN + 63) / 64;    // 17
        for (int it2 = wv; it2 < WIT; it2 += 4) {
            int g = it2 * 64 + l;
            int pix = g >> 3, slot = g & 7;
            int srcg = slot ^ (pix & 7);
            int gp = t0 + pix;
            if (gp > 361) gp = 361;              // pad row 361 is zeroed
            const u16* src = A + ((size_t)b * 362 + gp) * 576 + cs * 64 + srcg * 8;
            char* dst = sm + it2 * 1024 + l * 16;
            if (g < GRAN) glds16(src, dst);
        }
    };

    stage(0);
    loadB(0, 0);   // chunk = ky*9 + cs
    __syncthreads();

    #pragma unroll
    for (int cs = 0; cs < 9; ++cs) {
        #pragma unroll
        for (int ky = 0; ky < 3; ++ky) {
            int cur = (cs * 3 + ky) & 1;       // compile-time (unrolled)
            if (ky < 2) loadB(cur ^ 1, (ky + 1) * 9 + cs);
            else if (cs < 8) loadB(cur ^ 1, cs + 1);
            short8 ah[2], al[2];
            #pragma unroll
            for (int mi = 0; mi < 2; ++mi) {
                int p = (wv * 2 + mi) * 16 + r + ky;
                int off = p * 128 + ((q ^ (p & 7)) << 4);
                ah[mi] = *(const short8*)(sm + off);
                al[mi] = *(const short8*)(sm + (off ^ 64));
            }
            // term-major: 6 independent MFMAs between dependent uses
            #pragma unroll
            for (int ni = 0; ni < 3; ++ni)
                #pragma unroll
                for (int mi = 0; mi < 2; ++mi)
                    acc[mi][ni] = __builtin_amdgcn_mfma_f32_16x16x32_bf16(ah[mi], Bh[cur][ni], acc[mi][ni], 0, 0, 0);
            #pragma unroll
            for (int ni = 0; ni < 3; ++ni)
                #pragma unroll
                for (int mi = 0; mi < 2; ++mi)
                    acc[mi][ni] = __builtin_amdgcn_mfma_f32_16x16x32_bf16(ah[mi], Bl[cur][ni], acc[mi][ni], 0, 0, 0);
            #pragma unroll
            for (int ni = 0; ni < 3; ++ni)
                #pragma unroll
                for (int mi = 0; mi < 2; ++mi)
                    acc[mi][ni] = __builtin_amdgcn_mfma_f32_16x16x32_bf16(al[mi], Bh[cur][ni], acc[mi][ni], 0, 0, 0);
        }
        __syncthreads();
        if (cs < 8) {
            stage(cs + 1);
            __syncthreads();
        }
    }

    // epilogue: bias + leaky store, accumulating per-thread t-partials
    float psum[3] = {0.f, 0.f, 0.f};
    #pragma unroll
    for (int ni = 0; ni < 3; ++ni) {
        int n = (nt * 3 + ni) * 16 + r;
        if (n >= NFB) continue;
        float bi0 = bia[n];
        #pragma unroll
        for (int mi = 0; mi < 2; ++mi) {
            int tb = t0 + (wv * 2 + mi) * 16 + q * 4;
            #pragma unroll
            for (int j = 0; j < 4; ++j) {
                int t = tb + j;
                if (t < NANG) {
                    float v = acc[mi][ni][j] + bi0;
                    v = (v >= 0.f) ? v : 0.1f * v;
                    sp2[((size_t)b * NANG + t) * NFB + n] = v;
                    psum[ni] += v;
                }
            }
        }
    }
    // reduce psum over q (shfl) then over waves (LDS), write part[b][tt][f]
    float* wred = (float*)sm;                 // 4 waves x 3 ni x 16 r
    #pragma unroll
    for (int ni = 0; ni < 3; ++ni) {
        float s = psum[ni];
        s += __shfl_down(s, 32, 64);
        s += __shfl_down(s, 16, 64);
        if (q == 0) wred[(wv * 3 + ni) * 16 + r] = s;
    }
    __syncthreads();
    if (tid < 48) {
        int ni = tid / 16, rr = tid % 16;
        float tot = wred[(0 * 3 + ni) * 16 + rr] + wred[(1 * 3 + ni) * 16 + rr]
                  + wred[(2 * 3 + ni) * 16 + rr] + wred[(3 * 3 + ni) * 16 + rr];
        int n = (nt * 3 + ni) * 16 + rr;
        if (n < NFB) part[((size_t)b * 3 + tt) * NFB + n] = tot;
    }
}

// ---------------------------------------------------------------------------
// FC: z (b, 64 pix, 257 f) NHWC f32 -> zfc (b, f, 32)
// ---------------------------------------------------------------------------
__global__ __launch_bounds__(256) void fc_kernel(
    const float* __restrict__ z, const float* __restrict__ fw,
    const float* __restrict__ fb, float* __restrict__ zfc)
{
    int bid = blockIdx.x;
    int ftile = bid % 33;
    int b = bid / 33;
    int j = threadIdx.x & 31;
    int f = ftile * 8 + (threadIdx.x >> 5);
    if (f >= 257) return;
    const float* zb = z + (size_t)b * 16448;
    float a = fb[j];
    #pragma unroll 8
    for (int s = 0; s < 64; ++s) a = fmaf(zb[s * 257 + f], fw[j * 64 + s], a);
    zfc[((size_t)b * 257 + f) * 32 + j] = a;
}

// ---------------------------------------------------------------------------
// Per-thread 4x4 Hermitian eigh (complex Jacobi, f64) -> Re(Un Un^H)
// 256-thread blocks for wave packing (identical per-thread math).
// ---------------------------------------------------------------------------
__global__ __launch_bounds__(256) void eigh_kernel(const float* __restrict__ z, double* __restrict__ rp)
{
    int idx = blockIdx.x * 256 + threadIdx.x;
    if (idx >= NB * NFB) return;
    const float* zr = z + (size_t)idx * 32;
    double Ar[4][4], Ai[4][4], Vr[4][4], Vi[4][4];
    #pragma unroll
    for (int m = 0; m < 4; ++m)
        #pragma unroll
        for (int n = 0; n < 4; ++n) {
            Ar[m][n] = 0.5 * ((double)zr[m * 8 + n] + (double)zr[n * 8 + m]);
            Ai[m][n] = 0.5 * ((double)zr[m * 8 + n + 4] - (double)zr[n * 8 + m + 4]);
            Vr[m][n] = (m == n) ? 1.0 : 0.0;
            Vi[m][n] = 0.0;
        }
    #pragma unroll
    for (int m = 0; m < 4; ++m) Ar[m][m] += 1e-5;

    for (int sweep = 0; sweep < 8; ++sweep) {
        #pragma unroll
        for (int p = 0; p < 3; ++p)
            #pragma unroll
            for (int qq = p + 1; qq < 4; ++qq) {
                double apr = Ar[p][qq], api = Ai[p][qq];
                double rmod = sqrt(apr * apr + api * api);
                if (rmod < 1e-300) continue;
                double cph = apr / rmod, sph = api / rmod;
                double tau = (Ar[qq][qq] - Ar[p][p]) / (2.0 * rmod);
                double t = (tau >= 0.0) ? (-1.0 / (tau + sqrt(1.0 + tau * tau)))
                                        : (1.0 / (-tau + sqrt(1.0 + tau * tau)));
                double c = 1.0 / sqrt(1.0 + t * t);
                double s = t * c;
                double wr = s * cph, wi = s * sph;
                #pragma unroll
                for (int i = 0; i < 4; ++i) {
                    double xr = Ar[i][p], xi = Ai[i][p];
                    double yr = Ar[i][qq], yi = Ai[i][qq];
                    Ar[i][p] = c * xr + (wr * yr + wi * yi);
                    Ai[i][p] = c * xi + (wr * yi - wi * yr);
                    Ar[i][qq] = c * yr - (wr * xr - wi * xi);
                    Ai[i][qq] = c * yi - (wr * xi + wi * xr);
                }
                #pragma unroll
                for (int i = 0; i < 4; ++i) {
                    double xr = Ar[p][i], xi = Ai[p][i];
                    double yr = Ar[qq][i], yi = Ai[qq][i];
                    Ar[p][i] = c * xr + (wr * yr - wi * yi);
                    Ai[p][i] = c * xi + (wr * yi + wi * yr);
                    Ar[qq][i] = c * yr - (wr * xr + wi * xi);
                    Ai[qq][i] = c * yi - (wr * xi - wi * xr);
                }
                #pragma unroll
                for (int i = 0; i < 4; ++i) {
                    double xr = Vr[i][p], xi = Vi[i][p];
                    double yr = Vr[i][qq], yi = Vi[i][qq];
                    Vr[i][p] = c * xr + (wr * yr + wi * yi);
                    Vi[i][p] = c * xi + (wr * yi - wi * yr);
                    Vr[i][qq] = c * yr - (wr * xr - wi * xi);
                    Vi[i][qq] = c * yi - (wr * xi + wi * xr);
                }
            }
    }
    double ev[4] = {Ar[0][0], Ar[1][1], Ar[2][2], Ar[3][3]};
    int i0 = 0;
    #pragma unroll
    for (int k = 1; k < 4; ++k) if (ev[k] < ev[i0]) i0 = k;
    int i1 = (i0 == 0) ? 1 : 0;
    #pragma unroll
    for (int k = 0; k < 4; ++k) if (k != i0 && ev[k] < ev[i1]) i1 = k;
    double* o = rp + (size_t)idx * 16;
    #pragma unroll
    for (int m = 0; m < 4; ++m)
        #pragma unroll
        for (int n = 0; n < 4; ++n)
            o[m * 4 + n] = Vr[m][i0] * Vr[n][i0] + Vi[m][i0] * Vi[n][i0]
                         + Vr[m][i1] * Vr[n][i1] + Vi[m][i1] * Vi[n][i1];
}

// ---------------------------------------------------------------------------
// MUSIC spectrum -> unified mu (b, t=a+1 in 362, 9 sections of [hi32|lo32]).
// Symmetric 10-term quadratic form (P symmetric; off-diag pre-doubled) +
// all-loads-prefetched (8 in-flight per thread) for MLP.  [round-12 optimum]
// ---------------------------------------------------------------------------
__global__ __launch_bounds__(256) void music_kernel(
    const float4* __restrict__ svr, const float4* __restrict__ svi,
    const double* __restrict__ rp, u16* __restrict__ mu)
{
    __shared__ double P[32][10];
    __shared__ float T[32][33];
    int bid = blockIdx.x;
    int at = bid % 12; bid /= 12;
    int ft = bid % 9;
    int b = bid / 9;
    int f0 = ft * 32, a0 = at * 32;
    int tid = threadIdx.x;
    // stage P compressed: j -> (m,n) pairs; off-diag doubled
    for (int i = tid; i < 32 * 10; i += 256) {
        int fi = i / 10, j = i % 10;
        const int mm[10] = {0, 1, 2, 3, 0, 0, 0, 1, 1, 2};
        const int nn[10] = {0, 1, 2, 3, 1, 2, 3, 2, 3, 3};
        int f = f0 + fi;
        double v = 0.0;
        if (f < 257) {
            v = rp[((size_t)b * 257 + f) * 16 + mm[j] * 4 + nn[j]];
            if (j >= 4) v += v;
        }
        P[fi][j] = v;
    }
    __syncthreads();
    int asub = tid & 31, fsub = tid >> 5;
    int a = a0 + asub;
    bool av = (a < 360);
    // prefetch ALL loads (8 independent) before any f64 compute
    float4 u[4], w[4];
    #pragma unroll
    for (int k2 = 0; k2 < 4; ++k2) {
        int f = f0 + fsub + 8 * k2;
        u[k2] = (float4){0.f, 0.f, 0.f, 0.f};
        w[k2] = (float4){0.f, 0.f, 0.f, 0.f};
        if (av && f < 257) {
            u[k2] = svr[((size_t)b * 257 + f) * 360 + a];
            w[k2] = svi[((size_t)b * 257 + f) * 360 + a];
        }
    }
    #pragma unroll
    for (int k2 = 0; k2 < 4; ++k2) {
        int fl = fsub + 8 * k2;
        double ua[4] = {u[k2].x, u[k2].y, u[k2].z, u[k2].w};
        double wa[4] = {w[k2].x, w[k2].y, w[k2].z, w[k2].w};
        const double* Pf = P[fl];
        const int mm[10] = {0, 1, 2, 3, 0, 0, 0, 1, 1, 2};
        const int nn[10] = {0, 1, 2, 3, 1, 2, 3, 2, 3, 3};
        double den = 0.0;
        #pragma unroll
        for (int j = 0; j < 10; ++j)
            den += Pf[j] * (ua[mm[j]] * ua[nn[j]] - wa[mm[j]] * wa[nn[j]]);
        T[asub][fl] = (float)(1.0 / fmax(den, 1e-6));
    }
    __syncthreads();
    int sec0 = f0 >> 5;
    #pragma unroll
    for (int p = 0; p < 4; ++p) {
        int row = p * 8 + (tid >> 5);
        int fc = tid & 31;
        int a2 = a0 + row;
        if (a2 < 360) {
            float v = T[row][fc];
            u16* d = mu + ((size_t)b * 362 + a2 + 1) * 576 + (size_t)sec0 * 64 + fc;
            u16 hh = f2bf(v);
            d[0] = hh;
            d[32] = f2bf(v - bf2f(hh));
        }
    }
}

// ---------------------------------------------------------------------------
// attention finish (mean -> MLP -> sigmoid); part has 3 chunks per b.
// h-dot parallelized: 16 h x 16 threads.
// ---------------------------------------------------------------------------
__global__ __launch_bounds__(256) void attn_finish(
    const float* __restrict__ part, const float* __restrict__ w1,
    const float* __restrict__ w2, float* __restrict__ att)
{
    __shared__ float ys[257];
    __shared__ float hp[16][17];
    __shared__ float hs[16];
    int b = blockIdx.x;
    int tid = threadIdx.x;
    for (int f = tid; f < 257; f += 256) {
        float s = part[((size_t)b * 3 + 0) * 257 + f]
                + part[((size_t)b * 3 + 1) * 257 + f]
                + part[((size_t)b * 3 + 2) * 257 + f];
        ys[f] = s * (1.0f / 360.0f);
    }
    __syncthreads();
    {
        int h = tid >> 4, seg = tid & 15;
        float p = 0.f;
        for (int c = seg; c < 257; c += 16)
            p = fmaf(ys[c], w1[(size_t)h * 257 + c], p);
        hp[h][seg] = p;
    }
    __syncthreads();
    if (tid < 16) {
        float s = 0.f;
        #pragma unroll
        for (int k = 0; k < 16; ++k) s += hp[tid][k];
        hs[tid] = fmaxf(s, 0.f);
    }
    __syncthreads();
    for (int o = tid; o < 257; o += 256) {
        float a = 0.f;
        #pragma unroll
        for (int j = 0; j < 16; ++j) a = fmaf(hs[j], w2[(size_t)o * 16 + j], a);
        att[(size_t)b * 257 + o] = 1.0f / (1.0f + expf(-a));
    }
}

// ---------------------------------------------------------------------------
// conv1d 257->1 over att-weighted sp2(b,t,f), sigmoid -> outS (b,360)
// ---------------------------------------------------------------------------
__global__ __launch_bounds__(256) void convs1_kernel(
    const float* __restrict__ sp2, const float* __restrict__ att,
    const float* __restrict__ w, const float* __restrict__ bb,
    float* __restrict__ outS)
{
    int bid = blockIdx.x;
    int tt = bid % 90;
    int b = bid / 90;
    int wv = threadIdx.x >> 6, l = threadIdx.x & 63;
    int t = tt * 4 + wv;
    float s = 0.f;
    for (int f = l; f < 257; f += 64) {
        float av = att[(size_t)b * 257 + f];
        float w0 = w[f * 3] * av, w1 = w[f * 3 + 1] * av, w2 = w[f * 3 + 2] * av;
        const float* col = sp2 + (size_t)b * 360 * 257 + f;
        if (t > 0)   s = fmaf(w0, col[(size_t)(t - 1) * 257], s);
        s = fmaf(w1, col[(size_t)t * 257], s);
        if (t < 359) s = fmaf(w2, col[(size_t)(t + 1) * 257], s);
    }
    #pragma unroll
    for (int off = 32; off > 0; off >>= 1) s += __shfl_down(s, off, 64);
    if (l == 0) outS[(size_t)b * 360 + t] = 1.0f / (1.0f + expf(-(s + bb[0])));
}

// ---------------------------------------------------------------------------
// top-5 soft-argmax, wave-parallel (strict >, index asc tie-break)
// ---------------------------------------------------------------------------
__global__ __launch_bounds__(64) void doa_kernel(const float* __restrict__ spec, float* __restrict__ doa)
{
    int b = blockIdx.x;
    int l = threadIdx.x;
    const float* s = spec + (size_t)b * NANG;
    float v[6];
    #pragma unroll
    for (int j = 0; j < 6; ++j) {
        int idx = l + 64 * j;
        v[j] = (idx < NANG) ? s[idx] : -3.4e38f;
    }
    float wvv[5]; int wii[5];
    #pragma unroll
    for (int k = 0; k < 5; ++k) {
        float bv = v[0]; int bj = 0;
        #pragma unroll
        for (int j = 1; j < 6; ++j)
            if (v[j] > bv) { bv = v[j]; bj = j; }
        int bi = l + 64 * bj;
        #pragma unroll
        for (int off = 1; off < 64; off <<= 1) {
            float ov = __shfl_xor(bv, off, 64);
            int oi = __shfl_xor(bi, off, 64);
            if (ov > bv || (ov == bv && oi < bi)) { bv = ov; bi = oi; }
        }
        wvv[k] = bv; wii[k] = bi;
        if ((bi & 63) == l) {
            int j = bi >> 6;
            #pragma unroll
            for (int jj = 0; jj < 6; ++jj)
                if (jj == j) v[jj] = -3.4e38f;
        }
    }
    if (l == 0) {
        float m = wvv[0];
        float wsum = 0.f, asum = 0.f;
        #pragma unroll
        for (int k = 0; k < 5; ++k) {
            float e = expf(20.0f * (wvv[k] - m));
            wsum += e;
            asum += e * (float)wii[k];
        }
        doa[b] = asum / wsum;
    }
}

// ---------------------------------------------------------------------------
extern "C" void kernel_launch(void* const* d_in, const int* in_sizes, int n_in,
                              void* d_out, int out_size, void* d_ws, size_t ws_size,
                              hipStream_t stream)
{
    const float* X    = (const float*)d_in[0];
    const float* svr  = (const float*)d_in[1];
    const float* svi  = (const float*)d_in[2];
    const float* c1w  = (const float*)d_in[4];
    const float* c2w  = (const float*)d_in[5];
    const float* c3w  = (const float*)d_in[6];
    const float* c4w  = (const float*)d_in[7];
    const float* fcw  = (const float*)d_in[8];
    const float* fcb  = (const float*)d_in[9];
    const float* s2w  = (const float*)d_in[10];
    const float* s2b  = (const float*)d_in[11];
    const float* s1w  = (const float*)d_in[12];
    const float* s1b  = (const float*)d_in[13];
    const float* caw1 = (const float*)d_in[14];
    const float* caw2 = (const float*)d_in[15];
    const float* bn1g = (const float*)d_in[16]; const float* bn1b = (const float*)d_in[17];
    const float* bn1m = (const float*)d_in[18]; const float* bn1v = (const float*)d_in[19];
    const float* bn2g = (const float*)d_in[20]; const float* bn2b = (const float*)d_in[21];
    const float* bn2m = (const float*)d_in[22]; const float* bn2v = (const float*)d_in[23];
    const float* bn3g = (const float*)d_in[24]; const float* bn3b = (const float*)d_in[25];
    const float* bn3m = (const float*)d_in[26]; const float* bn3v = (const float*)d_in[27];
    const float* bn4g = (const float*)d_in[28]; const float* bn4b = (const float*)d_in[29];
    const float* bn4m = (const float*)d_in[30]; const float* bn4v = (const float*)d_in[31];

    char* wsb = (char*)d_ws;
    // region A (time-disjoint: xp -> c3 -> mu)
    u16* xp = (u16*)(wsb + 0);               // 34,611,200 B (64x130x130x32B)
    u16* c3 = (u16*)(wsb + 0);               // 18,939,904 B (64x34x34x256B)
    u16* mu = (u16*)(wsb + 0);               // 26,689,536 B (64x362x1152B)
    // region B (c2 -> {zbuf, zfc, rp, sp2, part, att})
    const size_t Bb = 34611200;
    u16*   c2  = (u16*)(wsb + Bb);           // 71,368,704 B (64x66x66x256B)
    float*  zbuf = (float*)(wsb + Bb);
    float*  zfc  = (float*)(wsb + Bb + 4210688);
    double* rp   = (double*)(wsb + Bb + 6316032);
    float*  sp2  = (float*)(wsb + Bb + 8421376);
    float*  part = (float*)(wsb + Bb + 32106496);
    float*  att  = (float*)(wsb + Bb + 32501248);
    // region C (persistent small)
    const size_t Cb = Bb + 71368704;
    u16* c4  = (u16*)(wsb + Cb);             // 5,308,416 B (64x18x18x256B)
    u16* bp1 = (u16*)(wsb + Cb + 5308416);
    u16* bp2 = (u16*)(wsb + Cb + 5382144);
    u16* bp3 = (u16*)(wsb + Cb + 5529600);
    u16* bp4 = (u16*)(wsb + Cb + 5677056);
    u16* bp5 = (u16*)(wsb + Cb + 6414336);
    float* bns = (float*)(wsb + Cb + 7409664);

    float* outD = (float*)d_out;
    float* outS = (float*)d_out + 64;

    // --- fused prep (bnprep + all bpacks + xpack) + fused init zpads ---
    prep_kernel<<<8825, 256, 0, stream>>>(
        X, xp, c1w, bp1, c2w, bp2, c3w, bp3, c4w, bp4, s2w, bp5,
        bn1g, bn1b, bn1m, bn1v, bn2g, bn2b, bn2m, bn2v,
        bn3g, bn3b, bn3m, bn3v, bn4g, bn4b, bn4m, bn4v, bns);
    zpad_init<<<2048, 256, 0, stream>>>((u32*)c2, (u32*)c4);

    // --- conv1 (3-term) ---
    conv_c1<<<64 * 64, 256, 0, stream>>>(xp, bp1, bns, bns + 512, c2);
    zpad<<<2112, 256, 0, stream>>>((u32*)c3, 64, 34, 34, 64, 1);   // A region free now
    // --- conv2 (3-term) ---
    conv_gemm<64, 64, 64, 2, 4, 2, 0, 4>
        <<<dim3(64 * 32, 1), 256, 0, stream>>>(c2, bp2, bns + 1024, bns + 1536, c3, nullptr);
    // --- conv3 (3-term) ---
    conv_gemm<32, 32, 64, 4, 4, 2, 0, 4>
        <<<dim3(64 * 8, 1), 256, 0, stream>>>(c3, bp3, bns + 2048, bns + 2560, c4, nullptr);
    zpad<<<144, 256, 0, stream>>>((u32*)mu, 64, 362, 1, 288, 0);   // A region free now
    // --- conv4 (3-term) -> z f32 (b,8,8,257) ---
    conv_gemm<16, 16, 257, 8, 4, 2, 1, 20>
        <<<dim3(64 * 2, 5), 256, 0, stream>>>(c4, bp4, bns + 3072, bns + 3584, nullptr, zbuf);

    fc_kernel<<<64 * 33, 256, 0, stream>>>(zbuf, fcw, fcb, zfc);
    eigh_kernel<<<65, 256, 0, stream>>>(zfc, rp);
    music_kernel<<<64 * 108, 256, 0, stream>>>((const float4*)svr, (const float4*)svi, rp, mu);
    // --- convs2 (3-term, +fused attention partial sums) -> sp2, part ---
    convs2_gemm<<<dim3(64 * 3, 6), 256, 0, stream>>>(mu, bp5, s2b, sp2, part);

    attn_finish<<<64, 256, 0, stream>>>(part, caw1, caw2, att);
    convs1_kernel<<<64 * 90, 256, 0, stream>>>(sp2, att, s1w, s1b, outS);
    doa_kernel<<<64, 64, 0, stream>>>(outS, outD);
}